// Round 19
// baseline (413.040 us; speedup 1.0000x reference)
//
#include <hip/hip_runtime.h>
#include <math.h>

// Problem constants
#define L_LAYERS 2
#define DM   128
#define DI   256
#define DS   16
#define DTR  8
#define DFF  256
#define PLEN 16
#define BSEQ 32
#define TSEQ 1024
#define MTOK (BSEQ*TSEQ)   // 32768
#define NCH  32            // scan chunks
#define CSZ  32            // TSEQ/NCH

typedef unsigned short ushort_t;
typedef __attribute__((ext_vector_type(8))) short short8;
typedef __attribute__((ext_vector_type(4))) float f32x4;
#define MFMA16(a,b,c) __builtin_amdgcn_mfma_f32_16x16x32_bf16(a,b,c,0,0,0)

__device__ __forceinline__ float silu_f(float x){ return x / (1.f + __expf(-x)); }
__device__ __forceinline__ float gelu_f(float x){ return 0.5f*x*(1.f + erff(x*0.7071067811865475f)); }
// Fast softplus: delta is consumed ONLY via its bf16 rounding, so the
// hardware-fast __logf (vs library log1pf) yields the identical bf16 in
// ~all cases (rel err ~1e-7 << bf16 eps 4e-3). v>20 guard unchanged.
__device__ __forceinline__ float softplus_f(float x){
    return (x > 20.f) ? x : __logf(1.f + __expf(x));
}

__device__ __forceinline__ ushort_t f2bf(float f){
    unsigned int u = __float_as_uint(f);
    u += 0x7fffu + ((u >> 16) & 1u);
    return (ushort_t)(u >> 16);
}
__device__ __forceinline__ float bf2f(ushort_t h){
    return __uint_as_float(((unsigned int)h) << 16);
}

// Check A[s] ~= A[0]*(s+1) (true for the reference A_log = log(1..16) tiled).
__device__ __forceinline__ bool a_structured(const float* A){
    bool ok = (A[0] < 0.f);
#pragma unroll
    for (int s=1;s<16;s++){
        float r = A[s]/A[0];
        ok = ok && (fabsf(r - (float)(s+1)) <= 1e-3f);
    }
    return ok;
}

// ---------------------------------------------------------------------------
// Patch embedding -> h (single bf16 plane)
__global__ __launch_bounds__(256) void patch_embed(
    const float* __restrict__ x, const float* __restrict__ Wp,
    const float* __restrict__ bp, ushort_t* __restrict__ hB)
{
    int bv = blockIdx.x, n0 = blockIdx.y * 64;
    __shared__ float xs[PLEN][64];
    __shared__ float ws[PLEN][DM];
    __shared__ float bs[DM];
    int tid = threadIdx.x;
    {
        int c = tid & 63, r0 = tid >> 6;
        for (int p = r0; p < PLEN; p += 4)
            xs[p][c] = x[bv*(PLEN*TSEQ) + p*TSEQ + n0 + c];
    }
    for (int i = tid; i < DM*PLEN; i += 256) {
        int d = i >> 4, p = i & 15;
        ws[p][d] = Wp[i];
    }
    if (tid < DM) bs[tid] = bp[tid];
    __syncthreads();
    int tm = tid & 15;
    int tn = tid >> 4;
    float acc[4][8];
#pragma unroll
    for (int i=0;i<4;i++)
#pragma unroll
        for (int j=0;j<8;j++) acc[i][j] = bs[tn*8+j];
#pragma unroll
    for (int p=0;p<PLEN;p++) {
        float4 a = *(const float4*)&xs[p][tm*4];
        float4 w0 = *(const float4*)&ws[p][tn*8];
        float4 w1 = *(const float4*)&ws[p][tn*8+4];
        const float* ap = (const float*)&a;
        const float* wp0 = (const float*)&w0;
        const float* wp1 = (const float*)&w1;
#pragma unroll
        for (int i=0;i<4;i++){
#pragma unroll
            for (int j=0;j<4;j++){
                acc[i][j]   += ap[i]*wp0[j];
                acc[i][j+4] += ap[i]*wp1[j];
            }
        }
    }
#pragma unroll
    for (int i=0;i<4;i++){
        size_t row = (size_t)(bv*TSEQ + n0 + tm*4 + i)*DM + tn*8;
        short8 hv;
#pragma unroll
        for (int j=0;j<8;j++) hv[j] = (short)f2bf(acc[i][j]);
        *(short8*)&hB[row] = hv;
    }
}

// ---------------------------------------------------------------------------
// Per-layer weight prep: fp32 -> bf16 (hi-plane only).
// wcS = raw bf16(xpW[0..39]) padded to 48 rows.
#define PREP_ELEMS 176128
__global__ __launch_bounds__(256) void prep_layer(
    const float* __restrict__ inW, const float* __restrict__ xpW,
    const float* __restrict__ outW,
    const float* __restrict__ l1W, const float* __restrict__ l2W,
    ushort_t* __restrict__ inWh, ushort_t* __restrict__ wcS,
    ushort_t* __restrict__ outWh,
    ushort_t* __restrict__ l1Wh, ushort_t* __restrict__ l2Wh)
{
    int e = blockIdx.x*256 + threadIdx.x;
    if (e >= PREP_ELEMS) return;
    float v; ushort_t *dh; int o;
    if (e < 65536){
        v = inW[e]; dh = inWh; o = e;
    } else if (e < 77824){
        int ee = e - 65536;           // 0..12287
        int n = ee >> 8, k = ee & 255;
        v = (n < 40) ? xpW[n*256 + k] : 0.f;
        dh = wcS; o = ee;
    } else if (e < 110592){
        int ee = e - 77824; v = outW[ee]; dh = outWh; o = ee;
    } else if (e < 143360){
        int ee = e - 110592; v = l1W[ee]; dh = l1Wh; o = ee;
    } else {
        int ee = e - 143360; v = l2W[ee]; dh = l2Wh; o = ee;
    }
    dh[o] = f2bf(v);
}

// ---------------------------------------------------------------------------
// Fused in_proj GEMM + causal depthwise conv (width 4) + bias + SiLU.
// Single-plane bf16 weights (R13, validated).
__global__ __launch_bounds__(256) void gemm_inproj_conv(
    const ushort_t* __restrict__ A,
    const ushort_t* __restrict__ WH,
    const float* __restrict__ cw, const float* __restrict__ cb,
    ushort_t* __restrict__ xcB, ushort_t* __restrict__ zB)
{
    constexpr int KT = 128, NT = 64, NCHK = KT/8;
    constexpr int XSS = 68;                     // xs row stride (shorts)
    __shared__ __align__(16) char smem[259*XSS*2 + 64*5*4 + 64*4];
    ushort_t* sWh = (ushort_t*)smem;            // 8192 shorts
    ushort_t* xs  = (ushort_t*)smem;            // union with sW (after barrier)
    float* cws = (float*)(smem + 259*XSS*2);    // [c*5+k]
    float* cbs = cws + 64*5;

    int m0 = blockIdx.x*256, n0 = blockIdx.y*NT;
    bool is_x = (n0 < 256);
    int tid = threadIdx.x;
    for (int i = tid; i < NT*NCHK; i += 256) {
        int nrow = i / NCHK, c = i % NCHK;
        int cs = c ^ (nrow & 7);
        *(short8*)&sWh[nrow*KT + cs*8] = *(const short8*)&WH[(size_t)(n0+nrow)*KT + c*8];
    }
    if (is_x){
        { int c = tid >> 2, k = tid & 3; cws[c*5+k] = cw[(n0+c)*4 + k]; }
        if (tid < 64) cbs[tid] = cb[n0+tid];
    }
    __syncthreads();
    int wave = tid>>6, lane = tid&63;
    int r = lane&15, g = lane>>4;
    int mw = m0 + wave*64;
    f32x4 acc[4][4];
#pragma unroll
    for (int i=0;i<4;i++)
#pragma unroll
        for (int j=0;j<4;j++) acc[i][j] = (f32x4){0.f,0.f,0.f,0.f};
#pragma unroll
    for (int ks = 0; ks < KT/32; ks++){
        short8 ah[4];
#pragma unroll
        for (int i=0;i<4;i++){
            size_t ga = (size_t)(mw + i*16 + r)*KT + ks*32 + g*8;
            ah[i] = *(const short8*)&A[ga];
        }
        short8 wh[4];
#pragma unroll
        for (int j=0;j<4;j++){
            int nrow = j*16 + r;
            int cs = (ks*4 + g) ^ (nrow & 7);
            wh[j] = *(const short8*)&sWh[nrow*KT + cs*8];
        }
#pragma unroll
        for (int i=0;i<4;i++)
#pragma unroll
        for (int j=0;j<4;j++){
            acc[i][j] = MFMA16(ah[i], wh[j], acc[i][j]);
        }
    }
    if (!is_x){
#pragma unroll
        for (int i=0;i<4;i++)
#pragma unroll
        for (int j=0;j<4;j++)
#pragma unroll
        for (int q=0;q<4;q++){
            int mm = mw + i*16 + g*4 + q;
            int nn = n0 - 256 + j*16 + r;
            zB[(size_t)mm*DI + nn] = f2bf(acc[i][j][q]);
        }
        return;
    }
    float bacc = 0.f;
    bool bvalid = ((m0 & 1023) != 0);
    if (tid < 192 && bvalid){
        int brow = tid >> 6, bcol = tid & 63;
        const ushort_t* hrow = A  + (size_t)(m0 - 3 + brow)*KT;
        const ushort_t* wrh  = WH + (size_t)(n0 + bcol)*KT;
#pragma unroll 8
        for (int k=0;k<KT;k++)
            bacc += bf2f(hrow[k]) * bf2f(wrh[k]);
    }
    __syncthreads();   // all sW reads done -> safe to overwrite with xs
    if (tid < 192){
        int brow = tid >> 6, bcol = tid & 63;
        xs[brow*XSS + bcol] = bvalid ? f2bf(bacc) : (ushort_t)0;
    }
#pragma unroll
    for (int i=0;i<4;i++)
#pragma unroll
    for (int j=0;j<4;j++)
#pragma unroll
    for (int q=0;q<4;q++){
        int mm = mw + i*16 + g*4 + q;
        xs[(mm - m0 + 3)*XSS + j*16 + r] = f2bf(acc[i][j][q]);
    }
    __syncthreads();
    for (int p = 0; p < 64; p++){
        int idx = p*256 + tid;
        int t = idx >> 6, cl = idx & 63;
        float v = cbs[cl];
#pragma unroll
        for (int k=0;k<4;k++) v += cws[cl*5+k]*bf2f(xs[(t+k)*XSS + cl]);
        xcB[(size_t)(m0 + t)*DI + n0 + cl] = f2bf(silu_f(v));
    }
}

// ---------------------------------------------------------------------------
// x_proj, rank-8 factored + inline scan pass 1, 512 threads (R17).
// bf16 state planes in the coalesced layout (R18). R19: fast softplus.
__global__ __launch_bounds__(512) void gemm_xproj(
    const ushort_t* __restrict__ A,        // xcB [M][256] bf16
    const ushort_t* __restrict__ WS,       // wcS [48][256] bf16
    const float* __restrict__ dtw,         // dt_proj_w [256][8] fp32
    const float* __restrict__ bias,        // dtB [256]
    const float* __restrict__ Alog,        // [256][16]
    unsigned int* __restrict__ duB, float* __restrict__ xbcF,
    ushort_t* __restrict__ hloc, float* __restrict__ sd)
{
    constexpr int KT = 256, NT = 48, MT = 64;
    constexpr int NCHK = KT/8;              // 32
    __shared__ ushort_t sW[NT*KT];          // 24576 B
    __shared__ __align__(16) float dtS[MT][8];   // 2048 B
    __shared__ __align__(16) float BsL[MT][16];  // 4096 B
    int m0 = blockIdx.x*MT;
    int tid = threadIdx.x;
    for (int i = tid; i < NT*NCHK; i += 512) {
        int nrow = i / NCHK, c = i % NCHK;
        int cs = c ^ (nrow & 7);
        *(short8*)&sW[nrow*KT + cs*8] = *(const short8*)&WS[(size_t)nrow*KT + c*8];
    }
    __syncthreads();
    // Phase 1: 8 waves = m-tile (wave&3) x n-part (wave>>2).
    {
        int wave = tid>>6, lane = tid&63;
        int r = lane&15, g = lane>>4;
        int mi = wave & 3, part = wave >> 2;
        int NJ = (part == 0) ? 2 : 1;
        int mw = m0 + mi*16;
        f32x4 acc[2];
#pragma unroll
        for (int j=0;j<2;j++) acc[j] = (f32x4){0.f,0.f,0.f,0.f};
#pragma unroll
        for (int ks = 0; ks < KT/32; ks++){
            short8 ah = *(const short8*)&A[(size_t)(mw + r)*KT + ks*32 + g*8];
#pragma unroll
            for (int j=0;j<2;j++){
                if (j < NJ){
                    int nrow = (part*2 + j)*16 + r;
                    int cs = (ks*4 + g) ^ (nrow & 7);
                    short8 wh = *(const short8*)&sW[nrow*KT + cs*8];
                    acc[j] = MFMA16(ah, wh, acc[j]);
                }
            }
        }
        // Epilogue: dt -> LDS, B -> LDS + xbcF, C -> xbcF
#pragma unroll
        for (int j=0;j<2;j++){
            if (j < NJ){
                int nn = (part*2 + j)*16 + r;
#pragma unroll
                for (int q=0;q<4;q++){
                    int mm = mw + g*4 + q;
                    float v = acc[j][q];
                    if (nn < 8){
                        dtS[mm - m0][nn] = v;
                    } else if (nn < 40){
                        xbcF[(size_t)mm*32 + (nn - 8)] = v;
                        if (nn < 24) BsL[mm - m0][nn - 8] = v;
                    }
                }
            }
        }
    }
    __syncthreads();
    // Phase 2: delta expansion + pack, fused chunk-local scan (h0 = 0).
    {
        int half = tid >> 8;
        int d = tid & 255;
        float4 dw0 = *(const float4*)&dtw[d*8];
        float4 dw1 = *(const float4*)&dtw[d*8 + 4];
        float bd = bias[d];
        float A0; bool structured;
        {
            float4 a0 = *(const float4*)&Alog[d*16];
            float4 a1 = *(const float4*)&Alog[d*16+4];
            float4 a2 = *(const float4*)&Alog[d*16+8];
            float4 a3 = *(const float4*)&Alog[d*16+12];
            float tmp[16] = {a0.x,a0.y,a0.z,a0.w,a1.x,a1.y,a1.z,a1.w,
                             a2.x,a2.y,a2.z,a2.w,a3.x,a3.y,a3.z,a3.w};
            float At[16];
#pragma unroll
            for (int s=0;s<16;s++) At[s] = -__expf(tmp[s]);
            structured = a_structured(At);
            A0 = At[0];
        }
        int b  = m0 >> 10;            // TSEQ = 1024
        int c  = ((m0 & 1023) >> 5) + half;
        float h[16];
#pragma unroll
        for (int s=0;s<16;s++) h[s] = 0.f;
        float sdv = 0.f;
#pragma unroll
        for (int t0 = 0; t0 < CSZ; t0 += 8){
            ushort_t uu[8];
#pragma unroll
            for (int k=0;k<8;k++)
                uu[k] = A[(size_t)(m0 + half*CSZ + t0 + k)*KT + d];
#pragma unroll
            for (int k=0;k<8;k++){
                int t = half*CSZ + t0 + k;
                const float* dt8 = dtS[t];
                float4 a0 = *(const float4*)&dt8[0];
                float4 a1 = *(const float4*)&dt8[4];
                float v = bd + a0.x*dw0.x + a0.y*dw0.y + a0.z*dw0.z + a0.w*dw0.w
                             + a1.x*dw1.x + a1.y*dw1.y + a1.z*dw1.z + a1.w*dw1.w;
                float delta = softplus_f(v);
                ushort_t dh = f2bf(delta);
                duB[(size_t)(m0 + t)*KT + d] =
                    ((unsigned int)dh << 16) | (unsigned int)uu[k];
                // inline pass1 (rounded values = what the scan consumes)
                float dlt = bf2f(dh);
                float uv  = bf2f(uu[k]);
                sdv += dlt;
                float duv = dlt*uv;
                const float4* Bp = (const float4*)&BsL[t][0];
                if (structured){
                    float p  = __expf(dlt*A0);
                    float p2 = p*p, p4 = p2*p2;
                    float f1 = p, f2 = p2, f3 = p2*p, f4 = p4;
#pragma unroll
                    for (int q=0;q<4;q++){
                        float4 bq = Bp[q];
                        h[4*q+0] = f1*h[4*q+0] + duv*bq.x;
                        h[4*q+1] = f2*h[4*q+1] + duv*bq.y;
                        h[4*q+2] = f3*h[4*q+2] + duv*bq.z;
                        h[4*q+3] = f4*h[4*q+3] + duv*bq.w;
                        if (q < 3){ f1 *= p4; f2 *= p4; f3 *= p4; f4 *= p4; }
                    }
                } else {
#pragma unroll
                    for (int q=0;q<4;q++){
                        float4 aq = *(const float4*)&Alog[d*16 + 4*q];
                        float4 bq = Bp[q];
                        h[4*q+0] = __expf(-dlt*__expf(aq.x))*h[4*q+0] + duv*bq.x;
                        h[4*q+1] = __expf(-dlt*__expf(aq.y))*h[4*q+1] + duv*bq.y;
                        h[4*q+2] = __expf(-dlt*__expf(aq.z))*h[4*q+2] + duv*bq.z;
                        h[4*q+3] = __expf(-dlt*__expf(aq.w))*h[4*q+3] + duv*bq.w;
                    }
                }
            }
        }
#pragma unroll
        for (int s=0;s<16;s++)
            hloc[((size_t)((b*NCH + c)*16 + s))*DI + d] = f2bf(h[s]);
        sd[(b*NCH + c)*DI + d] = sdv;
    }
}

// ---------------------------------------------------------------------------
// Prefix-combine over chunks (thread = (b,s,d)) — coalesced layout, bf16
// states. R19: software prefetch — the loads are independent of the serial
// hs chain, so fetch chunk c+1 while combining chunk c.
__global__ __launch_bounds__(256) void scan_combine(
    const ushort_t* __restrict__ hloc, const float* __restrict__ sd,
    const float* __restrict__ Alog, ushort_t* __restrict__ hstart)
{
    int b = blockIdx.x, s = blockIdx.y;
    int d = threadIdx.x;
    float A = -__expf(Alog[d*16+s]);
    float hs = 0.f;
    size_t base0 = ((size_t)((b*NCH + 0)*16 + s))*DI + d;
    ushort_t hl_cur = hloc[base0];
    float    sd_cur = sd[(b*NCH + 0)*DI + d];
    for (int c = 0; c < NCH; c++){
        size_t base = ((size_t)((b*NCH + c)*16 + s))*DI + d;
        ushort_t hl_nxt = 0; float sd_nxt = 0.f;
        if (c + 1 < NCH){
            size_t basen = ((size_t)((b*NCH + c + 1)*16 + s))*DI + d;
            hl_nxt = hloc[basen];
            sd_nxt = sd[(b*NCH + c + 1)*DI + d];
        }
        hstart[base] = f2bf(hs);
        hs = __expf(sd_cur*A)*hs + bf2f(hl_cur);
        hl_cur = hl_nxt; sd_cur = sd_nxt;
    }
}

// ---------------------------------------------------------------------------
// Fused scan pass 2 + out_proj + FFN (gelu) for a 32-token chunk.
// Phase A: TWO loads per token (packed du 4B + z 2B), depth-8 double-buffer.
// h-init from bf16 hstart (same coalesced layout).
// Phase B: SINGLE-plane bf16 weights (R12, validated).
__global__ __launch_bounds__(256,4) void scan_fused(
    const unsigned int* __restrict__ duB, const float* __restrict__ xbcF,
    const ushort_t* __restrict__ zB,
    const float* __restrict__ Alog, const float* __restrict__ Dp,
    const ushort_t* __restrict__ hstart,
    const ushort_t* __restrict__ oWh,
    const ushort_t* __restrict__ w1h,
    const float* __restrict__ b1,
    const ushort_t* __restrict__ w2h,
    const float* __restrict__ b2,
    ushort_t* __restrict__ hB)
{
    constexpr int YS = DI + 8;    // 264 shorts
    constexpr int OS = DM + 8;    // 136 shorts
    __shared__ __align__(16) ushort_t smem[CSZ*YS + CSZ*OS];   // 25600 B
    ushort_t* yB = smem;                      // [t*YS + d]
    ushort_t* oB = smem + CSZ*YS;             // [t*OS + n]
    float*    Bs = (float*)(smem + CSZ*YS);   // union with oB
    float*    Cs = Bs + CSZ*16;

    int b = blockIdx.x, c = blockIdx.y;
    int tid = threadIdx.x;
    int mbase = b*TSEQ + c*CSZ;
    for (int i = tid; i < CSZ*32; i += 256) {
        int t = i >> 5, s2 = i & 31;
        float v = xbcF[(size_t)(mbase+t)*32 + s2];
        if (s2 < 16) Bs[t*16+s2] = v; else Cs[t*16+s2-16] = v;
    }
    // ---- Phase A: scan
    {
        int d = tid;
        // group-0 register prefetch: overlaps barrier + A/hstart setup
        unsigned int du[2][8]; ushort_t zz[2][8];
#pragma unroll
        for (int k=0;k<8;k++){
            size_t m = (size_t)(mbase+k);
            du[0][k] = duB[m*DI + d];
            zz[0][k] = zB[m*DI + d];
        }
        float A0; bool structured;
        {
            float4 a0 = *(const float4*)&Alog[d*16];
            float4 a1 = *(const float4*)&Alog[d*16+4];
            float4 a2 = *(const float4*)&Alog[d*16+8];
            float4 a3 = *(const float4*)&Alog[d*16+12];
            float tmp[16] = {a0.x,a0.y,a0.z,a0.w,a1.x,a1.y,a1.z,a1.w,
                             a2.x,a2.y,a2.z,a2.w,a3.x,a3.y,a3.z,a3.w};
            float At[16];
#pragma unroll
            for (int s=0;s<16;s++) At[s] = -__expf(tmp[s]);
            structured = a_structured(At);
            A0 = At[0];
        }
        float h[16];
#pragma unroll
        for (int s=0;s<16;s++)
            h[s] = bf2f(hstart[((size_t)((b*NCH + c)*16 + s))*DI + d]);
        float Dd = Dp[d];
        __syncthreads();
        if (structured){
#pragma unroll
            for (int t0i = 0; t0i < CSZ/8; t0i++){
                int cur = t0i & 1, nxt = cur ^ 1;   // static after unroll
                if (t0i < CSZ/8 - 1){
#pragma unroll
                    for (int k=0;k<8;k++){
                        size_t m = (size_t)(mbase + (t0i+1)*8 + k);
                        du[nxt][k] = duB[m*DI + d];
                        zz[nxt][k] = zB[m*DI + d];
                    }
                }
#pragma unroll
                for (int k=0;k<8;k++){
                    int t = t0i*8 + k;
                    unsigned int pk_ = du[cur][k];
                    float dlt = bf2f((ushort_t)(pk_ >> 16));
                    float uv  = bf2f((ushort_t)(pk_ & 0xffffu));
                    float duv = dlt*uv;
                    float p  = __expf(dlt*A0);
                    float p2 = p*p, p4 = p2*p2;
                    float f1 = p, f2 = p2, f3 = p2*p, f4 = p4;
                    const float4* Bp = (const float4*)&Bs[t*16];
                    const float4* Cp = (const float4*)&Cs[t*16];
                    float y0=0.f, y1=0.f, y2=0.f, y3=0.f;
#pragma unroll
                    for (int q=0;q<4;q++){
                        float4 bq = Bp[q];
                        float4 cq = Cp[q];
                        h[4*q+0] = f1*h[4*q+0] + duv*bq.x; y0 += h[4*q+0]*cq.x;
                        h[4*q+1] = f2*h[4*q+1] + duv*bq.y; y1 += h[4*q+1]*cq.y;
                        h[4*q+2] = f3*h[4*q+2] + duv*bq.z; y2 += h[4*q+2]*cq.z;
                        h[4*q+3] = f4*h[4*q+3] + duv*bq.w; y3 += h[4*q+3]*cq.w;
                        if (q < 3){ f1 *= p4; f2 *= p4; f3 *= p4; f4 *= p4; }
                    }
                    float y = (y0+y1)+(y2+y3);
                    yB[t*YS+d] = f2bf((y + uv*Dd) * silu_f(bf2f(zz[cur][k])));
                }
            }
        } else {
            // cold fallback: general A (reloaded from global per 4-state group)
            for (int t = 0; t < CSZ; t++){
                size_t m = (size_t)(mbase+t);
                unsigned int pk_ = duB[m*DI + d];
                float dlt = bf2f((ushort_t)(pk_ >> 16));
                float uv  = bf2f((ushort_t)(pk_ & 0xffffu));
                float zv  = bf2f(zB[m*DI + d]);
                float duv = dlt*uv;
                float y0=0.f, y1=0.f, y2=0.f, y3=0.f;
#pragma unroll
                for (int q=0;q<4;q++){
                    float4 aq = *(const float4*)&Alog[d*16 + 4*q];
                    float4 bq = *(const float4*)&Bs[t*16 + 4*q];
                    float4 cq = *(const float4*)&Cs[t*16 + 4*q];
                    h[4*q+0] = __expf(-dlt*__expf(aq.x))*h[4*q+0] + duv*bq.x; y0 += h[4*q+0]*cq.x;
                    h[4*q+1] = __expf(-dlt*__expf(aq.y))*h[4*q+1] + duv*bq.y; y1 += h[4*q+1]*cq.y;
                    h[4*q+2] = __expf(-dlt*__expf(aq.z))*h[4*q+2] + duv*bq.z; y2 += h[4*q+2]*cq.z;
                    h[4*q+3] = __expf(-dlt*__expf(aq.w))*h[4*q+3] + duv*bq.w; y3 += h[4*q+3]*cq.w;
                }
                float y = (y0+y1)+(y2+y3);
                yB[t*YS+d] = f2bf((y + uv*Dd) * silu_f(zv));
            }
        }
    }
    __syncthreads();   // yB done; Bs/Cs dead -> region2 reusable as oB
    // ---- Phase B (single-plane bf16 weights)
    int wave = tid>>6, lane = tid&63;
    int r = lane&15, g = lane>>4;
    // Stage 1: o[32][128] = y @ oW^T  (K=256)
    {
        f32x4 s1[2][2];
#pragma unroll
        for (int i=0;i<2;i++)
#pragma unroll
            for (int j=0;j<2;j++) s1[i][j] = (f32x4){0.f,0.f,0.f,0.f};
#pragma unroll
        for (int ks=0;ks<8;ks++){
            short8 ya[2];
#pragma unroll
            for (int i=0;i<2;i++)
                ya[i] = *(const short8*)&yB[(i*16+r)*YS + ks*32 + g*8];
            short8 wh_[2];
#pragma unroll
            for (int j=0;j<2;j++){
                size_t wa = (size_t)(wave*32 + j*16 + r)*256 + ks*32 + g*8;
                wh_[j] = *(const short8*)&oWh[wa];
            }
#pragma unroll
            for (int i=0;i<2;i++)
#pragma unroll
            for (int j=0;j<2;j++){
                s1[i][j] = MFMA16(ya[i], wh_[j], s1[i][j]);
            }
        }
#pragma unroll
        for (int i=0;i<2;i++)
#pragma unroll
        for (int j=0;j<2;j++)
#pragma unroll
        for (int q=0;q<4;q++){
            int t = i*16 + g*4 + q;
            int n = wave*32 + j*16 + r;
            oB[t*OS+n] = f2bf(s1[i][j][q]);
        }
    }
    __syncthreads();   // oB ready; yB reads done
    // Stage 2: f[32][256] = gelu(o @ w1^T + b1)  (K=128), into yB
    {
        f32x4 s2[2][4];
#pragma unroll
        for (int i=0;i<2;i++)
#pragma unroll
            for (int j=0;j<4;j++) s2[i][j] = (f32x4){0.f,0.f,0.f,0.f};
#pragma unroll
        for (int ks=0;ks<4;ks++){
            short8 oa[2];
#pragma unroll
            for (int i=0;i<2;i++)
                oa[i] = *(const short8*)&oB[(i*16+r)*OS + ks*32 + g*8];
            short8 wh_[4];
#pragma unroll
            for (int j=0;j<4;j++){
                size_t wa = (size_t)(wave*64 + j*16 + r)*128 + ks*32 + g*8;
                wh_[j] = *(const short8*)&w1h[wa];
            }
#pragma unroll
            for (int i=0;i<2;i++)
#pragma unroll
            for (int j=0;j<4;j++){
                s2[i][j] = MFMA16(oa[i], wh_[j], s2[i][j]);
            }
        }
#pragma unroll
        for (int i=0;i<2;i++)
#pragma unroll
        for (int j=0;j<4;j++)
#pragma unroll
        for (int q=0;q<4;q++){
            int t = i*16 + g*4 + q;
            int n = wave*64 + j*16 + r;
            yB[t*YS+n] = f2bf(gelu_f(s2[i][j][q] + b1[n]));
        }
    }
    __syncthreads();   // f (in yB) done
    // Stage 3: hnew[32][128] = f @ w2^T + b2  (K=256) -> global plane
    {
        f32x4 s3[2][2];
#pragma unroll
        for (int i=0;i<2;i++)
#pragma unroll
            for (int j=0;j<2;j++) s3[i][j] = (f32x4){0.f,0.f,0.f,0.f};
#pragma unroll
        for (int ks=0;ks<8;ks++){
            short8 fa[2];
#pragma unroll
            for (int i=0;i<2;i++)
                fa[i] = *(const short8*)&yB[(i*16+r)*YS + ks*32 + g*8];
            short8 wh_[2];
#pragma unroll
            for (int j=0;j<2;j++){
                size_t wa = (size_t)(wave*32 + j*16 + r)*256 + ks*32 + g*8;
                wh_[j] = *(const short8*)&w2h[wa];
            }
#pragma unroll
            for (int i=0;i<2;i++)
#pragma unroll
            for (int j=0;j<2;j++){
                s3[i][j] = MFMA16(fa[i], wh_[j], s3[i][j]);
            }
        }
#pragma unroll
        for (int i=0;i<2;i++)
#pragma unroll
        for (int j=0;j<2;j++)
#pragma unroll
        for (int q=0;q<4;q++){
            int t = i*16 + g*4 + q;
            int n = wave*32 + j*16 + r;
            hB[(size_t)(mbase + t)*DM + n] = f2bf(s3[i][j][q] + b2[n]);
        }
    }
}

// ---------------------------------------------------------------------------
// Final transpose: out[bv, d, n] = h[bv*1024+n, d]
__global__ __launch_bounds__(256) void final_transpose(
    const ushort_t* __restrict__ hB, float* __restrict__ out)
{
    int n0 = blockIdx.x*32, d0 = blockIdx.y*32, bv = blockIdx.z;
    __shared__ float ts[32][33];
    int tid = threadIdx.x;
    int c = tid & 31, r0 = tid >> 5;
    for (int rr = r0; rr < 32; rr += 8)
        ts[rr][c] = bf2f(hB[(size_t)(bv*TSEQ + n0 + rr)*DM + d0 + c]);
    __syncthreads();
    for (int rr = r0; rr < 32; rr += 8)
        out[(size_t)(bv*DM + d0 + rr)*TSEQ + n0 + c] = ts[c][rr];
}

// ---------------------------------------------------------------------------
extern "C" void kernel_launch(void* const* d_in, const int* in_sizes, int n_in,
                              void* d_out, int out_size, void* d_ws, size_t ws_size,
                              hipStream_t stream)
{
    const float* x     = (const float*)d_in[0];
    const float* Wp    = (const float*)d_in[1];
    const float* Wpb   = (const float*)d_in[2];
    const float* inW   = (const float*)d_in[3];
    const float* convW = (const float*)d_in[4];
    const float* convB = (const float*)d_in[5];
    const float* xpW   = (const float*)d_in[6];
    const float* dtW   = (const float*)d_in[7];
    const float* dtB   = (const float*)d_in[8];
    const float* Alog  = (const float*)d_in[9];
    const float* Dp    = (const float*)d_in[10];
    const float* outW  = (const float*)d_in[11];
    const float* l1W   = (const float*)d_in[12];
    const float* l1B   = (const float*)d_in[13];
    const float* l2W   = (const float*)d_in[14];
    const float* l2B   = (const float*)d_in[15];
    float* out = (float*)d_out;

    char* base = (char*)d_ws;
    size_t off = 0;
    auto alloc = [&](size_t bytes) { char* p = base + off; off += (bytes + 255) & ~(size_t)255; return p; };

    const size_t P128 = (size_t)MTOK*DM*2;     // [M][128] bf16 plane
    const size_t P256 = (size_t)MTOK*DI*2;     // [M][256] bf16 plane

    ushort_t* hB  = (ushort_t*)alloc(P128);
    unsigned int* duB = (unsigned int*)alloc((size_t)MTOK*DI*4);  // delta|u packed
    float* xbcF   = (float*)alloc((size_t)MTOK*32*4);             // B|C fp32
    ushort_t* zB  = (ushort_t*)alloc(P256);
    ushort_t* xcB = (ushort_t*)alloc(P256);
    ushort_t* hloc   = (ushort_t*)alloc((size_t)BSEQ*NCH*DS*DI*2);  // bf16 states
    ushort_t* hstart = (ushort_t*)alloc((size_t)BSEQ*NCH*DS*DI*2);  // bf16 states
    float* sd     = (float*)alloc((size_t)BSEQ*NCH*DI*4);
    ushort_t* inWh  = (ushort_t*)alloc((size_t)512*128*2);
    ushort_t* wcS   = (ushort_t*)alloc((size_t)48*256*2);
    ushort_t* outWh = (ushort_t*)alloc((size_t)128*256*2);
    ushort_t* l1Wh  = (ushort_t*)alloc((size_t)256*128*2);
    ushort_t* l2Wh  = (ushort_t*)alloc((size_t)128*256*2);

    patch_embed<<<dim3(32,16), 256, 0, stream>>>(x, Wp, Wpb, hB);

    for (int L = 0; L < L_LAYERS; L++) {
        const float* inW_l   = inW   + (size_t)L*2*DI*DM;
        const float* convW_l = convW + (size_t)L*DI*4;
        const float* convB_l = convB + (size_t)L*DI;
        const float* xpW_l   = xpW   + (size_t)L*(DTR+2*DS)*DI;
        const float* dtW_l   = dtW   + (size_t)L*DI*DTR;
        const float* dtB_l   = dtB   + (size_t)L*DI;
        const float* Alog_l  = Alog  + (size_t)L*DI*DS;
        const float* Dp_l    = Dp    + (size_t)L*DI;
        const float* outW_l  = outW  + (size_t)L*DM*DI;
        const float* l1W_l   = l1W   + (size_t)L*DFF*DM;
        const float* l1B_l   = l1B   + (size_t)L*DFF;
        const float* l2W_l   = l2W   + (size_t)L*DM*DFF;
        const float* l2B_l   = l2B   + (size_t)L*DM;

        prep_layer<<<(PREP_ELEMS+255)/256, 256, 0, stream>>>(
            inW_l, xpW_l, outW_l, l1W_l, l2W_l,
            inWh, wcS, outWh, l1Wh, l2Wh);

        gemm_inproj_conv<<<dim3(MTOK/256, 8), 256, 0, stream>>>(
            hB, inWh, convW_l, convB_l, xcB, zB);
        gemm_xproj<<<dim3(MTOK/64), 512, 0, stream>>>(
            xcB, wcS, dtW_l, dtB_l, Alog_l, duB, xbcF, hloc, sd);
        scan_combine<<<dim3(BSEQ, DS), 256, 0, stream>>>(
            hloc, sd, Alog_l, hstart);
        scan_fused<<<dim3(BSEQ, NCH), 256, 0, stream>>>(
            duB, xbcF, zB, Alog_l, Dp_l, hstart,
            outWh, l1Wh, l1B_l, l2Wh, l2B_l, hB);
    }

    final_transpose<<<dim3(TSEQ/32, DM/32, BSEQ), 256, 0, stream>>>(hB, out);
}

// Round 20
// 312.720 us; speedup vs baseline: 1.3208x; 1.3208x over previous
//
#include <hip/hip_runtime.h>
#include <math.h>

// Problem constants
#define L_LAYERS 2
#define DM   128
#define DI   256
#define DS   16
#define DTR  8
#define DFF  256
#define PLEN 16
#define BSEQ 32
#define TSEQ 1024
#define MTOK (BSEQ*TSEQ)   // 32768
#define NCH  32            // scan chunks
#define CSZ  32            // TSEQ/NCH

typedef unsigned short ushort_t;
typedef __attribute__((ext_vector_type(8))) short short8;
typedef __attribute__((ext_vector_type(4))) float f32x4;
#define MFMA16(a,b,c) __builtin_amdgcn_mfma_f32_16x16x32_bf16(a,b,c,0,0,0)

__device__ __forceinline__ float silu_f(float x){ return x / (1.f + __expf(-x)); }
__device__ __forceinline__ float gelu_f(float x){ return 0.5f*x*(1.f + erff(x*0.7071067811865475f)); }
// Fast softplus (R19, kept): delta is consumed ONLY via its bf16 rounding,
// so hardware __logf/__expf yields the identical bf16 in ~all cases.
__device__ __forceinline__ float softplus_f(float x){
    return (x > 20.f) ? x : __logf(1.f + __expf(x));
}

__device__ __forceinline__ ushort_t f2bf(float f){
    unsigned int u = __float_as_uint(f);
    u += 0x7fffu + ((u >> 16) & 1u);
    return (ushort_t)(u >> 16);
}
__device__ __forceinline__ float bf2f(ushort_t h){
    return __uint_as_float(((unsigned int)h) << 16);
}

// Check A[s] ~= A[0]*(s+1) (true for the reference A_log = log(1..16) tiled).
__device__ __forceinline__ bool a_structured(const float* A){
    bool ok = (A[0] < 0.f);
#pragma unroll
    for (int s=1;s<16;s++){
        float r = A[s]/A[0];
        ok = ok && (fabsf(r - (float)(s+1)) <= 1e-3f);
    }
    return ok;
}

// ---------------------------------------------------------------------------
// Patch embedding -> h (single bf16 plane)
__global__ __launch_bounds__(256) void patch_embed(
    const float* __restrict__ x, const float* __restrict__ Wp,
    const float* __restrict__ bp, ushort_t* __restrict__ hB)
{
    int bv = blockIdx.x, n0 = blockIdx.y * 64;
    __shared__ float xs[PLEN][64];
    __shared__ float ws[PLEN][DM];
    __shared__ float bs[DM];
    int tid = threadIdx.x;
    {
        int c = tid & 63, r0 = tid >> 6;
        for (int p = r0; p < PLEN; p += 4)
            xs[p][c] = x[bv*(PLEN*TSEQ) + p*TSEQ + n0 + c];
    }
    for (int i = tid; i < DM*PLEN; i += 256) {
        int d = i >> 4, p = i & 15;
        ws[p][d] = Wp[i];
    }
    if (tid < DM) bs[tid] = bp[tid];
    __syncthreads();
    int tm = tid & 15;
    int tn = tid >> 4;
    float acc[4][8];
#pragma unroll
    for (int i=0;i<4;i++)
#pragma unroll
        for (int j=0;j<8;j++) acc[i][j] = bs[tn*8+j];
#pragma unroll
    for (int p=0;p<PLEN;p++) {
        float4 a = *(const float4*)&xs[p][tm*4];
        float4 w0 = *(const float4*)&ws[p][tn*8];
        float4 w1 = *(const float4*)&ws[p][tn*8+4];
        const float* ap = (const float*)&a;
        const float* wp0 = (const float*)&w0;
        const float* wp1 = (const float*)&w1;
#pragma unroll
        for (int i=0;i<4;i++){
#pragma unroll
            for (int j=0;j<4;j++){
                acc[i][j]   += ap[i]*wp0[j];
                acc[i][j+4] += ap[i]*wp1[j];
            }
        }
    }
#pragma unroll
    for (int i=0;i<4;i++){
        size_t row = (size_t)(bv*TSEQ + n0 + tm*4 + i)*DM + tn*8;
        short8 hv;
#pragma unroll
        for (int j=0;j<8;j++) hv[j] = (short)f2bf(acc[i][j]);
        *(short8*)&hB[row] = hv;
    }
}

// ---------------------------------------------------------------------------
// Per-layer weight prep: fp32 -> bf16 (hi-plane only).
// wcS = raw bf16(xpW[0..39]) padded to 48 rows.
#define PREP_ELEMS 176128
__global__ __launch_bounds__(256) void prep_layer(
    const float* __restrict__ inW, const float* __restrict__ xpW,
    const float* __restrict__ outW,
    const float* __restrict__ l1W, const float* __restrict__ l2W,
    ushort_t* __restrict__ inWh, ushort_t* __restrict__ wcS,
    ushort_t* __restrict__ outWh,
    ushort_t* __restrict__ l1Wh, ushort_t* __restrict__ l2Wh)
{
    int e = blockIdx.x*256 + threadIdx.x;
    if (e >= PREP_ELEMS) return;
    float v; ushort_t *dh; int o;
    if (e < 65536){
        v = inW[e]; dh = inWh; o = e;
    } else if (e < 77824){
        int ee = e - 65536;           // 0..12287
        int n = ee >> 8, k = ee & 255;
        v = (n < 40) ? xpW[n*256 + k] : 0.f;
        dh = wcS; o = ee;
    } else if (e < 110592){
        int ee = e - 77824; v = outW[ee]; dh = outWh; o = ee;
    } else if (e < 143360){
        int ee = e - 110592; v = l1W[ee]; dh = l1Wh; o = ee;
    } else {
        int ee = e - 143360; v = l2W[ee]; dh = l2Wh; o = ee;
    }
    dh[o] = f2bf(v);
}

// ---------------------------------------------------------------------------
// Fused in_proj GEMM + causal depthwise conv (width 4) + bias + SiLU.
// Single-plane bf16 weights (R13, validated).
__global__ __launch_bounds__(256) void gemm_inproj_conv(
    const ushort_t* __restrict__ A,
    const ushort_t* __restrict__ WH,
    const float* __restrict__ cw, const float* __restrict__ cb,
    ushort_t* __restrict__ xcB, ushort_t* __restrict__ zB)
{
    constexpr int KT = 128, NT = 64, NCHK = KT/8;
    constexpr int XSS = 68;                     // xs row stride (shorts)
    __shared__ __align__(16) char smem[259*XSS*2 + 64*5*4 + 64*4];
    ushort_t* sWh = (ushort_t*)smem;            // 8192 shorts
    ushort_t* xs  = (ushort_t*)smem;            // union with sW (after barrier)
    float* cws = (float*)(smem + 259*XSS*2);    // [c*5+k]
    float* cbs = cws + 64*5;

    int m0 = blockIdx.x*256, n0 = blockIdx.y*NT;
    bool is_x = (n0 < 256);
    int tid = threadIdx.x;
    for (int i = tid; i < NT*NCHK; i += 256) {
        int nrow = i / NCHK, c = i % NCHK;
        int cs = c ^ (nrow & 7);
        *(short8*)&sWh[nrow*KT + cs*8] = *(const short8*)&WH[(size_t)(n0+nrow)*KT + c*8];
    }
    if (is_x){
        { int c = tid >> 2, k = tid & 3; cws[c*5+k] = cw[(n0+c)*4 + k]; }
        if (tid < 64) cbs[tid] = cb[n0+tid];
    }
    __syncthreads();
    int wave = tid>>6, lane = tid&63;
    int r = lane&15, g = lane>>4;
    int mw = m0 + wave*64;
    f32x4 acc[4][4];
#pragma unroll
    for (int i=0;i<4;i++)
#pragma unroll
        for (int j=0;j<4;j++) acc[i][j] = (f32x4){0.f,0.f,0.f,0.f};
#pragma unroll
    for (int ks = 0; ks < KT/32; ks++){
        short8 ah[4];
#pragma unroll
        for (int i=0;i<4;i++){
            size_t ga = (size_t)(mw + i*16 + r)*KT + ks*32 + g*8;
            ah[i] = *(const short8*)&A[ga];
        }
        short8 wh[4];
#pragma unroll
        for (int j=0;j<4;j++){
            int nrow = j*16 + r;
            int cs = (ks*4 + g) ^ (nrow & 7);
            wh[j] = *(const short8*)&sWh[nrow*KT + cs*8];
        }
#pragma unroll
        for (int i=0;i<4;i++)
#pragma unroll
        for (int j=0;j<4;j++){
            acc[i][j] = MFMA16(ah[i], wh[j], acc[i][j]);
        }
    }
    if (!is_x){
#pragma unroll
        for (int i=0;i<4;i++)
#pragma unroll
        for (int j=0;j<4;j++)
#pragma unroll
        for (int q=0;q<4;q++){
            int mm = mw + i*16 + g*4 + q;
            int nn = n0 - 256 + j*16 + r;
            zB[(size_t)mm*DI + nn] = f2bf(acc[i][j][q]);
        }
        return;
    }
    float bacc = 0.f;
    bool bvalid = ((m0 & 1023) != 0);
    if (tid < 192 && bvalid){
        int brow = tid >> 6, bcol = tid & 63;
        const ushort_t* hrow = A  + (size_t)(m0 - 3 + brow)*KT;
        const ushort_t* wrh  = WH + (size_t)(n0 + bcol)*KT;
#pragma unroll 8
        for (int k=0;k<KT;k++)
            bacc += bf2f(hrow[k]) * bf2f(wrh[k]);
    }
    __syncthreads();   // all sW reads done -> safe to overwrite with xs
    if (tid < 192){
        int brow = tid >> 6, bcol = tid & 63;
        xs[brow*XSS + bcol] = bvalid ? f2bf(bacc) : (ushort_t)0;
    }
#pragma unroll
    for (int i=0;i<4;i++)
#pragma unroll
    for (int j=0;j<4;j++)
#pragma unroll
    for (int q=0;q<4;q++){
        int mm = mw + i*16 + g*4 + q;
        xs[(mm - m0 + 3)*XSS + j*16 + r] = f2bf(acc[i][j][q]);
    }
    __syncthreads();
    for (int p = 0; p < 64; p++){
        int idx = p*256 + tid;
        int t = idx >> 6, cl = idx & 63;
        float v = cbs[cl];
#pragma unroll
        for (int k=0;k<4;k++) v += cws[cl*5+k]*bf2f(xs[(t+k)*XSS + cl]);
        xcB[(size_t)(m0 + t)*DI + n0 + cl] = f2bf(silu_f(v));
    }
}

// ---------------------------------------------------------------------------
// x_proj, rank-8 factored + inline scan pass 1, 512 threads (R17).
// bf16 state planes in the coalesced layout (R18). Fast softplus (R19).
__global__ __launch_bounds__(512) void gemm_xproj(
    const ushort_t* __restrict__ A,        // xcB [M][256] bf16
    const ushort_t* __restrict__ WS,       // wcS [48][256] bf16
    const float* __restrict__ dtw,         // dt_proj_w [256][8] fp32
    const float* __restrict__ bias,        // dtB [256]
    const float* __restrict__ Alog,        // [256][16]
    unsigned int* __restrict__ duB, float* __restrict__ xbcF,
    ushort_t* __restrict__ hloc, float* __restrict__ sd)
{
    constexpr int KT = 256, NT = 48, MT = 64;
    constexpr int NCHK = KT/8;              // 32
    __shared__ ushort_t sW[NT*KT];          // 24576 B
    __shared__ __align__(16) float dtS[MT][8];   // 2048 B
    __shared__ __align__(16) float BsL[MT][16];  // 4096 B
    int m0 = blockIdx.x*MT;
    int tid = threadIdx.x;
    for (int i = tid; i < NT*NCHK; i += 512) {
        int nrow = i / NCHK, c = i % NCHK;
        int cs = c ^ (nrow & 7);
        *(short8*)&sW[nrow*KT + cs*8] = *(const short8*)&WS[(size_t)nrow*KT + c*8];
    }
    __syncthreads();
    // Phase 1: 8 waves = m-tile (wave&3) x n-part (wave>>2).
    {
        int wave = tid>>6, lane = tid&63;
        int r = lane&15, g = lane>>4;
        int mi = wave & 3, part = wave >> 2;
        int NJ = (part == 0) ? 2 : 1;
        int mw = m0 + mi*16;
        f32x4 acc[2];
#pragma unroll
        for (int j=0;j<2;j++) acc[j] = (f32x4){0.f,0.f,0.f,0.f};
#pragma unroll
        for (int ks = 0; ks < KT/32; ks++){
            short8 ah = *(const short8*)&A[(size_t)(mw + r)*KT + ks*32 + g*8];
#pragma unroll
            for (int j=0;j<2;j++){
                if (j < NJ){
                    int nrow = (part*2 + j)*16 + r;
                    int cs = (ks*4 + g) ^ (nrow & 7);
                    short8 wh = *(const short8*)&sW[nrow*KT + cs*8];
                    acc[j] = MFMA16(ah, wh, acc[j]);
                }
            }
        }
        // Epilogue: dt -> LDS, B -> LDS + xbcF, C -> xbcF
#pragma unroll
        for (int j=0;j<2;j++){
            if (j < NJ){
                int nn = (part*2 + j)*16 + r;
#pragma unroll
                for (int q=0;q<4;q++){
                    int mm = mw + g*4 + q;
                    float v = acc[j][q];
                    if (nn < 8){
                        dtS[mm - m0][nn] = v;
                    } else if (nn < 40){
                        xbcF[(size_t)mm*32 + (nn - 8)] = v;
                        if (nn < 24) BsL[mm - m0][nn - 8] = v;
                    }
                }
            }
        }
    }
    __syncthreads();
    // Phase 2: delta expansion + pack, fused chunk-local scan (h0 = 0).
    {
        int half = tid >> 8;
        int d = tid & 255;
        float4 dw0 = *(const float4*)&dtw[d*8];
        float4 dw1 = *(const float4*)&dtw[d*8 + 4];
        float bd = bias[d];
        float A0; bool structured;
        {
            float4 a0 = *(const float4*)&Alog[d*16];
            float4 a1 = *(const float4*)&Alog[d*16+4];
            float4 a2 = *(const float4*)&Alog[d*16+8];
            float4 a3 = *(const float4*)&Alog[d*16+12];
            float tmp[16] = {a0.x,a0.y,a0.z,a0.w,a1.x,a1.y,a1.z,a1.w,
                             a2.x,a2.y,a2.z,a2.w,a3.x,a3.y,a3.z,a3.w};
            float At[16];
#pragma unroll
            for (int s=0;s<16;s++) At[s] = -__expf(tmp[s]);
            structured = a_structured(At);
            A0 = At[0];
        }
        int b  = m0 >> 10;            // TSEQ = 1024
        int c  = ((m0 & 1023) >> 5) + half;
        float h[16];
#pragma unroll
        for (int s=0;s<16;s++) h[s] = 0.f;
        float sdv = 0.f;
#pragma unroll
        for (int t0 = 0; t0 < CSZ; t0 += 8){
            ushort_t uu[8];
#pragma unroll
            for (int k=0;k<8;k++)
                uu[k] = A[(size_t)(m0 + half*CSZ + t0 + k)*KT + d];
#pragma unroll
            for (int k=0;k<8;k++){
                int t = half*CSZ + t0 + k;
                const float* dt8 = dtS[t];
                float4 a0 = *(const float4*)&dt8[0];
                float4 a1 = *(const float4*)&dt8[4];
                float v = bd + a0.x*dw0.x + a0.y*dw0.y + a0.z*dw0.z + a0.w*dw0.w
                             + a1.x*dw1.x + a1.y*dw1.y + a1.z*dw1.z + a1.w*dw1.w;
                float delta = softplus_f(v);
                ushort_t dh = f2bf(delta);
                duB[(size_t)(m0 + t)*KT + d] =
                    ((unsigned int)dh << 16) | (unsigned int)uu[k];
                // inline pass1 (rounded values = what the scan consumes)
                float dlt = bf2f(dh);
                float uv  = bf2f(uu[k]);
                sdv += dlt;
                float duv = dlt*uv;
                const float4* Bp = (const float4*)&BsL[t][0];
                if (structured){
                    float p  = __expf(dlt*A0);
                    float p2 = p*p, p4 = p2*p2;
                    float f1 = p, f2 = p2, f3 = p2*p, f4 = p4;
#pragma unroll
                    for (int q=0;q<4;q++){
                        float4 bq = Bp[q];
                        h[4*q+0] = f1*h[4*q+0] + duv*bq.x;
                        h[4*q+1] = f2*h[4*q+1] + duv*bq.y;
                        h[4*q+2] = f3*h[4*q+2] + duv*bq.z;
                        h[4*q+3] = f4*h[4*q+3] + duv*bq.w;
                        if (q < 3){ f1 *= p4; f2 *= p4; f3 *= p4; f4 *= p4; }
                    }
                } else {
#pragma unroll
                    for (int q=0;q<4;q++){
                        float4 aq = *(const float4*)&Alog[d*16 + 4*q];
                        float4 bq = Bp[q];
                        h[4*q+0] = __expf(-dlt*__expf(aq.x))*h[4*q+0] + duv*bq.x;
                        h[4*q+1] = __expf(-dlt*__expf(aq.y))*h[4*q+1] + duv*bq.y;
                        h[4*q+2] = __expf(-dlt*__expf(aq.z))*h[4*q+2] + duv*bq.z;
                        h[4*q+3] = __expf(-dlt*__expf(aq.w))*h[4*q+3] + duv*bq.w;
                    }
                }
            }
        }
#pragma unroll
        for (int s=0;s<16;s++)
            hloc[((size_t)((b*NCH + c)*16 + s))*DI + d] = f2bf(h[s]);
        sd[(b*NCH + c)*DI + d] = sdv;
    }
}

// ---------------------------------------------------------------------------
// Prefix-combine over chunks (thread = (b,s,d)) — coalesced layout, bf16
// states (R18 form — the R19 prefetch rewrite is reverted; it coincided
// with an unexplained scan_fused slowdown and had no confirmed win).
__global__ __launch_bounds__(256) void scan_combine(
    const ushort_t* __restrict__ hloc, const float* __restrict__ sd,
    const float* __restrict__ Alog, ushort_t* __restrict__ hstart)
{
    int b = blockIdx.x, s = blockIdx.y;
    int d = threadIdx.x;
    float A = -__expf(Alog[d*16+s]);
    float hs = 0.f;
    for (int c = 0; c < NCH; c++){
        size_t base = ((size_t)((b*NCH + c)*16 + s))*DI + d;
        hstart[base] = f2bf(hs);
        float sdp = sd[(b*NCH + c)*DI + d];
        hs = __expf(sdp*A)*hs + bf2f(hloc[base]);
    }
}

// ---------------------------------------------------------------------------
// Fused scan pass 2 + out_proj + FFN (gelu) for a 32-token chunk.
// Phase A: TWO loads per token (packed du 4B + z 2B), depth-8 double-buffer.
// h-init from bf16 hstart (same coalesced layout).
// Phase B: SINGLE-plane bf16 weights (R12, validated).
__global__ __launch_bounds__(256,4) void scan_fused(
    const unsigned int* __restrict__ duB, const float* __restrict__ xbcF,
    const ushort_t* __restrict__ zB,
    const float* __restrict__ Alog, const float* __restrict__ Dp,
    const ushort_t* __restrict__ hstart,
    const ushort_t* __restrict__ oWh,
    const ushort_t* __restrict__ w1h,
    const float* __restrict__ b1,
    const ushort_t* __restrict__ w2h,
    const float* __restrict__ b2,
    ushort_t* __restrict__ hB)
{
    constexpr int YS = DI + 8;    // 264 shorts
    constexpr int OS = DM + 8;    // 136 shorts
    __shared__ __align__(16) ushort_t smem[CSZ*YS + CSZ*OS];   // 25600 B
    ushort_t* yB = smem;                      // [t*YS + d]
    ushort_t* oB = smem + CSZ*YS;             // [t*OS + n]
    float*    Bs = (float*)(smem + CSZ*YS);   // union with oB
    float*    Cs = Bs + CSZ*16;

    int b = blockIdx.x, c = blockIdx.y;
    int tid = threadIdx.x;
    int mbase = b*TSEQ + c*CSZ;
    for (int i = tid; i < CSZ*32; i += 256) {
        int t = i >> 5, s2 = i & 31;
        float v = xbcF[(size_t)(mbase+t)*32 + s2];
        if (s2 < 16) Bs[t*16+s2] = v; else Cs[t*16+s2-16] = v;
    }
    // ---- Phase A: scan
    {
        int d = tid;
        // group-0 register prefetch: overlaps barrier + A/hstart setup
        unsigned int du[2][8]; ushort_t zz[2][8];
#pragma unroll
        for (int k=0;k<8;k++){
            size_t m = (size_t)(mbase+k);
            du[0][k] = duB[m*DI + d];
            zz[0][k] = zB[m*DI + d];
        }
        float A0; bool structured;
        {
            float4 a0 = *(const float4*)&Alog[d*16];
            float4 a1 = *(const float4*)&Alog[d*16+4];
            float4 a2 = *(const float4*)&Alog[d*16+8];
            float4 a3 = *(const float4*)&Alog[d*16+12];
            float tmp[16] = {a0.x,a0.y,a0.z,a0.w,a1.x,a1.y,a1.z,a1.w,
                             a2.x,a2.y,a2.z,a2.w,a3.x,a3.y,a3.z,a3.w};
            float At[16];
#pragma unroll
            for (int s=0;s<16;s++) At[s] = -__expf(tmp[s]);
            structured = a_structured(At);
            A0 = At[0];
        }
        float h[16];
#pragma unroll
        for (int s=0;s<16;s++)
            h[s] = bf2f(hstart[((size_t)((b*NCH + c)*16 + s))*DI + d]);
        float Dd = Dp[d];
        __syncthreads();
        if (structured){
#pragma unroll
            for (int t0i = 0; t0i < CSZ/8; t0i++){
                int cur = t0i & 1, nxt = cur ^ 1;   // static after unroll
                if (t0i < CSZ/8 - 1){
#pragma unroll
                    for (int k=0;k<8;k++){
                        size_t m = (size_t)(mbase + (t0i+1)*8 + k);
                        du[nxt][k] = duB[m*DI + d];
                        zz[nxt][k] = zB[m*DI + d];
                    }
                }
#pragma unroll
                for (int k=0;k<8;k++){
                    int t = t0i*8 + k;
                    unsigned int pk_ = du[cur][k];
                    float dlt = bf2f((ushort_t)(pk_ >> 16));
                    float uv  = bf2f((ushort_t)(pk_ & 0xffffu));
                    float duv = dlt*uv;
                    float p  = __expf(dlt*A0);
                    float p2 = p*p, p4 = p2*p2;
                    float f1 = p, f2 = p2, f3 = p2*p, f4 = p4;
                    const float4* Bp = (const float4*)&Bs[t*16];
                    const float4* Cp = (const float4*)&Cs[t*16];
                    float y0=0.f, y1=0.f, y2=0.f, y3=0.f;
#pragma unroll
                    for (int q=0;q<4;q++){
                        float4 bq = Bp[q];
                        float4 cq = Cp[q];
                        h[4*q+0] = f1*h[4*q+0] + duv*bq.x; y0 += h[4*q+0]*cq.x;
                        h[4*q+1] = f2*h[4*q+1] + duv*bq.y; y1 += h[4*q+1]*cq.y;
                        h[4*q+2] = f3*h[4*q+2] + duv*bq.z; y2 += h[4*q+2]*cq.z;
                        h[4*q+3] = f4*h[4*q+3] + duv*bq.w; y3 += h[4*q+3]*cq.w;
                        if (q < 3){ f1 *= p4; f2 *= p4; f3 *= p4; f4 *= p4; }
                    }
                    float y = (y0+y1)+(y2+y3);
                    yB[t*YS+d] = f2bf((y + uv*Dd) * silu_f(bf2f(zz[cur][k])));
                }
            }
        } else {
            // cold fallback: general A (reloaded from global per 4-state group)
            for (int t = 0; t < CSZ; t++){
                size_t m = (size_t)(mbase+t);
                unsigned int pk_ = duB[m*DI + d];
                float dlt = bf2f((ushort_t)(pk_ >> 16));
                float uv  = bf2f((ushort_t)(pk_ & 0xffffu));
                float zv  = bf2f(zB[m*DI + d]);
                float duv = dlt*uv;
                float y0=0.f, y1=0.f, y2=0.f, y3=0.f;
#pragma unroll
                for (int q=0;q<4;q++){
                    float4 aq = *(const float4*)&Alog[d*16 + 4*q];
                    float4 bq = *(const float4*)&Bs[t*16 + 4*q];
                    float4 cq = *(const float4*)&Cs[t*16 + 4*q];
                    h[4*q+0] = __expf(-dlt*__expf(aq.x))*h[4*q+0] + duv*bq.x; y0 += h[4*q+0]*cq.x;
                    h[4*q+1] = __expf(-dlt*__expf(aq.y))*h[4*q+1] + duv*bq.y; y1 += h[4*q+1]*cq.y;
                    h[4*q+2] = __expf(-dlt*__expf(aq.z))*h[4*q+2] + duv*bq.z; y2 += h[4*q+2]*cq.z;
                    h[4*q+3] = __expf(-dlt*__expf(aq.w))*h[4*q+3] + duv*bq.w; y3 += h[4*q+3]*cq.w;
                }
                float y = (y0+y1)+(y2+y3);
                yB[t*YS+d] = f2bf((y + uv*Dd) * silu_f(zv));
            }
        }
    }
    __syncthreads();   // yB done; Bs/Cs dead -> region2 reusable as oB
    // ---- Phase B (single-plane bf16 weights)
    int wave = tid>>6, lane = tid&63;
    int r = lane&15, g = lane>>4;
    // Stage 1: o[32][128] = y @ oW^T  (K=256)
    {
        f32x4 s1[2][2];
#pragma unroll
        for (int i=0;i<2;i++)
#pragma unroll
            for (int j=0;j<2;j++) s1[i][j] = (f32x4){0.f,0.f,0.f,0.f};
#pragma unroll
        for (int ks=0;ks<8;ks++){
            short8 ya[2];
#pragma unroll
            for (int i=0;i<2;i++)
                ya[i] = *(const short8*)&yB[(i*16+r)*YS + ks*32 + g*8];
            short8 wh_[2];
#pragma unroll
            for (int j=0;j<2;j++){
                size_t wa = (size_t)(wave*32 + j*16 + r)*256 + ks*32 + g*8;
                wh_[j] = *(const short8*)&oWh[wa];
            }
#pragma unroll
            for (int i=0;i<2;i++)
#pragma unroll
            for (int j=0;j<2;j++){
                s1[i][j] = MFMA16(ya[i], wh_[j], s1[i][j]);
            }
        }
#pragma unroll
        for (int i=0;i<2;i++)
#pragma unroll
        for (int j=0;j<2;j++)
#pragma unroll
        for (int q=0;q<4;q++){
            int t = i*16 + g*4 + q;
            int n = wave*32 + j*16 + r;
            oB[t*OS+n] = f2bf(s1[i][j][q]);
        }
    }
    __syncthreads();   // oB ready; yB reads done
    // Stage 2: f[32][256] = gelu(o @ w1^T + b1)  (K=128), into yB
    {
        f32x4 s2[2][4];
#pragma unroll
        for (int i=0;i<2;i++)
#pragma unroll
            for (int j=0;j<4;j++) s2[i][j] = (f32x4){0.f,0.f,0.f,0.f};
#pragma unroll
        for (int ks=0;ks<4;ks++){
            short8 oa[2];
#pragma unroll
            for (int i=0;i<2;i++)
                oa[i] = *(const short8*)&oB[(i*16+r)*OS + ks*32 + g*8];
            short8 wh_[4];
#pragma unroll
            for (int j=0;j<4;j++){
                size_t wa = (size_t)(wave*64 + j*16 + r)*128 + ks*32 + g*8;
                wh_[j] = *(const short8*)&w1h[wa];
            }
#pragma unroll
            for (int i=0;i<2;i++)
#pragma unroll
            for (int j=0;j<4;j++){
                s2[i][j] = MFMA16(oa[i], wh_[j], s2[i][j]);
            }
        }
#pragma unroll
        for (int i=0;i<2;i++)
#pragma unroll
        for (int j=0;j<4;j++)
#pragma unroll
        for (int q=0;q<4;q++){
            int t = i*16 + g*4 + q;
            int n = wave*64 + j*16 + r;
            yB[t*YS+n] = f2bf(gelu_f(s2[i][j][q] + b1[n]));
        }
    }
    __syncthreads();   // f (in yB) done
    // Stage 3: hnew[32][128] = f @ w2^T + b2  (K=256) -> global plane
    {
        f32x4 s3[2][2];
#pragma unroll
        for (int i=0;i<2;i++)
#pragma unroll
            for (int j=0;j<2;j++) s3[i][j] = (f32x4){0.f,0.f,0.f,0.f};
#pragma unroll
        for (int ks=0;ks<8;ks++){
            short8 fa[2];
#pragma unroll
            for (int i=0;i<2;i++)
                fa[i] = *(const short8*)&yB[(i*16+r)*YS + ks*32 + g*8];
            short8 wh_[2];
#pragma unroll
            for (int j=0;j<2;j++){
                size_t wa = (size_t)(wave*32 + j*16 + r)*256 + ks*32 + g*8;
                wh_[j] = *(const short8*)&w2h[wa];
            }
#pragma unroll
            for (int i=0;i<2;i++)
#pragma unroll
            for (int j=0;j<2;j++){
                s3[i][j] = MFMA16(fa[i], wh_[j], s3[i][j]);
            }
        }
#pragma unroll
        for (int i=0;i<2;i++)
#pragma unroll
        for (int j=0;j<2;j++)
#pragma unroll
        for (int q=0;q<4;q++){
            int t = i*16 + g*4 + q;
            int n = wave*32 + j*16 + r;
            hB[(size_t)(mbase + t)*DM + n] = f2bf(s3[i][j][q] + b2[n]);
        }
    }
}

// ---------------------------------------------------------------------------
// Final transpose: out[bv, d, n] = h[bv*1024+n, d]
__global__ __launch_bounds__(256) void final_transpose(
    const ushort_t* __restrict__ hB, float* __restrict__ out)
{
    int n0 = blockIdx.x*32, d0 = blockIdx.y*32, bv = blockIdx.z;
    __shared__ float ts[32][33];
    int tid = threadIdx.x;
    int c = tid & 31, r0 = tid >> 5;
    for (int rr = r0; rr < 32; rr += 8)
        ts[rr][c] = bf2f(hB[(size_t)(bv*TSEQ + n0 + rr)*DM + d0 + c]);
    __syncthreads();
    for (int rr = r0; rr < 32; rr += 8)
        out[(size_t)(bv*DM + d0 + rr)*TSEQ + n0 + c] = ts[c][rr];
}

// ---------------------------------------------------------------------------
extern "C" void kernel_launch(void* const* d_in, const int* in_sizes, int n_in,
                              void* d_out, int out_size, void* d_ws, size_t ws_size,
                              hipStream_t stream)
{
    const float* x     = (const float*)d_in[0];
    const float* Wp    = (const float*)d_in[1];
    const float* Wpb   = (const float*)d_in[2];
    const float* inW   = (const float*)d_in[3];
    const float* convW = (const float*)d_in[4];
    const float* convB = (const float*)d_in[5];
    const float* xpW   = (const float*)d_in[6];
    const float* dtW   = (const float*)d_in[7];
    const float* dtB   = (const float*)d_in[8];
    const float* Alog  = (const float*)d_in[9];
    const float* Dp    = (const float*)d_in[10];
    const float* outW  = (const float*)d_in[11];
    const float* l1W   = (const float*)d_in[12];
    const float* l1B   = (const float*)d_in[13];
    const float* l2W   = (const float*)d_in[14];
    const float* l2B   = (const float*)d_in[15];
    float* out = (float*)d_out;

    char* base = (char*)d_ws;
    size_t off = 0;
    auto alloc = [&](size_t bytes) { char* p = base + off; off += (bytes + 255) & ~(size_t)255; return p; };

    const size_t P128 = (size_t)MTOK*DM*2;     // [M][128] bf16 plane
    const size_t P256 = (size_t)MTOK*DI*2;     // [M][256] bf16 plane

    ushort_t* hB  = (ushort_t*)alloc(P128);
    unsigned int* duB = (unsigned int*)alloc((size_t)MTOK*DI*4);  // delta|u packed
    float* xbcF   = (float*)alloc((size_t)MTOK*32*4);             // B|C fp32
    ushort_t* zB  = (ushort_t*)alloc(P256);
    ushort_t* xcB = (ushort_t*)alloc(P256);
    ushort_t* hloc   = (ushort_t*)alloc((size_t)BSEQ*NCH*DS*DI*2);  // bf16 states
    ushort_t* hstart = (ushort_t*)alloc((size_t)BSEQ*NCH*DS*DI*2);  // bf16 states
    float* sd     = (float*)alloc((size_t)BSEQ*NCH*DI*4);
    ushort_t* inWh  = (ushort_t*)alloc((size_t)512*128*2);
    ushort_t* wcS   = (ushort_t*)alloc((size_t)48*256*2);
    ushort_t* outWh = (ushort_t*)alloc((size_t)128*256*2);
    ushort_t* l1Wh  = (ushort_t*)alloc((size_t)256*128*2);
    ushort_t* l2Wh  = (ushort_t*)alloc((size_t)128*256*2);

    patch_embed<<<dim3(32,16), 256, 0, stream>>>(x, Wp, Wpb, hB);

    for (int L = 0; L < L_LAYERS; L++) {
        const float* inW_l   = inW   + (size_t)L*2*DI*DM;
        const float* convW_l = convW + (size_t)L*DI*4;
        const float* convB_l = convB + (size_t)L*DI;
        const float* xpW_l   = xpW   + (size_t)L*(DTR+2*DS)*DI;
        const float* dtW_l   = dtW   + (size_t)L*DI*DTR;
        const float* dtB_l   = dtB   + (size_t)L*DI;
        const float* Alog_l  = Alog  + (size_t)L*DI*DS;
        const float* Dp_l    = Dp    + (size_t)L*DI;
        const float* outW_l  = outW  + (size_t)L*DM*DI;
        const float* l1W_l   = l1W   + (size_t)L*DFF*DM;
        const float* l1B_l   = l1B   + (size_t)L*DFF;
        const float* l2W_l   = l2W   + (size_t)L*DM*DFF;
        const float* l2B_l   = l2B   + (size_t)L*DM;

        prep_layer<<<(PREP_ELEMS+255)/256, 256, 0, stream>>>(
            inW_l, xpW_l, outW_l, l1W_l, l2W_l,
            inWh, wcS, outWh, l1Wh, l2Wh);

        gemm_inproj_conv<<<dim3(MTOK/256, 8), 256, 0, stream>>>(
            hB, inWh, convW_l, convB_l, xcB, zB);
        gemm_xproj<<<dim3(MTOK/64), 512, 0, stream>>>(
            xcB, wcS, dtW_l, dtB_l, Alog_l, duB, xbcF, hloc, sd);
        scan_combine<<<dim3(BSEQ, DS), 256, 0, stream>>>(
            hloc, sd, Alog_l, hstart);
        scan_fused<<<dim3(BSEQ, NCH), 256, 0, stream>>>(
            duB, xbcF, zB, Alog_l, Dp_l, hstart,
            outWh, l1Wh, l1B_l, l2Wh, l2B_l, hB);
    }

    final_transpose<<<dim3(TSEQ/32, DM/32, BSEQ), 256, 0, stream>>>(hB, out);
}

// Round 21
// 312.293 us; speedup vs baseline: 1.3226x; 1.0014x over previous
//
#include <hip/hip_runtime.h>
#include <math.h>

// Problem constants
#define L_LAYERS 2
#define DM   128
#define DI   256
#define DS   16
#define DTR  8
#define DFF  256
#define PLEN 16
#define BSEQ 32
#define TSEQ 1024
#define MTOK (BSEQ*TSEQ)   // 32768
#define NCH  32            // scan chunks
#define CSZ  32            // TSEQ/NCH

typedef unsigned short ushort_t;
typedef __attribute__((ext_vector_type(8))) short short8;
typedef __attribute__((ext_vector_type(4))) float f32x4;
#define MFMA16(a,b,c) __builtin_amdgcn_mfma_f32_16x16x32_bf16(a,b,c,0,0,0)

__device__ __forceinline__ float silu_f(float x){ return x / (1.f + __expf(-x)); }
// Fast gelu (R21): tanh-form with hardware exp. Max abs err ~3e-4 — same
// class as the bf16 rounding the result immediately undergoes. Replaces the
// library erff (~20+ instrs) with ~8 VALU ops. (R20 lesson: library
// transcendentals dominate VALU-bound epilogues — log1pf removal was -44us.)
__device__ __forceinline__ float gelu_f(float x){
    float x3 = x*x*x;
    float t = __expf(1.5957691216f*x + 0.0713548162f*x3);  // exp(2*0.7978846*(x+0.044715x^3))
    return x * __fdividef(t, t + 1.f);
}
// Fast softplus (R19, validated): delta is consumed ONLY via its bf16
// rounding, so hardware __logf/__expf yields the identical bf16.
__device__ __forceinline__ float softplus_f(float x){
    return (x > 20.f) ? x : __logf(1.f + __expf(x));
}

__device__ __forceinline__ ushort_t f2bf(float f){
    unsigned int u = __float_as_uint(f);
    u += 0x7fffu + ((u >> 16) & 1u);
    return (ushort_t)(u >> 16);
}
__device__ __forceinline__ float bf2f(ushort_t h){
    return __uint_as_float(((unsigned int)h) << 16);
}

// Check A[s] ~= A[0]*(s+1) (true for the reference A_log = log(1..16) tiled).
__device__ __forceinline__ bool a_structured(const float* A){
    bool ok = (A[0] < 0.f);
#pragma unroll
    for (int s=1;s<16;s++){
        float r = A[s]/A[0];
        ok = ok && (fabsf(r - (float)(s+1)) <= 1e-3f);
    }
    return ok;
}

// ---------------------------------------------------------------------------
// Patch embedding -> h (single bf16 plane)
__global__ __launch_bounds__(256) void patch_embed(
    const float* __restrict__ x, const float* __restrict__ Wp,
    const float* __restrict__ bp, ushort_t* __restrict__ hB)
{
    int bv = blockIdx.x, n0 = blockIdx.y * 64;
    __shared__ float xs[PLEN][64];
    __shared__ float ws[PLEN][DM];
    __shared__ float bs[DM];
    int tid = threadIdx.x;
    {
        int c = tid & 63, r0 = tid >> 6;
        for (int p = r0; p < PLEN; p += 4)
            xs[p][c] = x[bv*(PLEN*TSEQ) + p*TSEQ + n0 + c];
    }
    for (int i = tid; i < DM*PLEN; i += 256) {
        int d = i >> 4, p = i & 15;
        ws[p][d] = Wp[i];
    }
    if (tid < DM) bs[tid] = bp[tid];
    __syncthreads();
    int tm = tid & 15;
    int tn = tid >> 4;
    float acc[4][8];
#pragma unroll
    for (int i=0;i<4;i++)
#pragma unroll
        for (int j=0;j<8;j++) acc[i][j] = bs[tn*8+j];
#pragma unroll
    for (int p=0;p<PLEN;p++) {
        float4 a = *(const float4*)&xs[p][tm*4];
        float4 w0 = *(const float4*)&ws[p][tn*8];
        float4 w1 = *(const float4*)&ws[p][tn*8+4];
        const float* ap = (const float*)&a;
        const float* wp0 = (const float*)&w0;
        const float* wp1 = (const float*)&w1;
#pragma unroll
        for (int i=0;i<4;i++){
#pragma unroll
            for (int j=0;j<4;j++){
                acc[i][j]   += ap[i]*wp0[j];
                acc[i][j+4] += ap[i]*wp1[j];
            }
        }
    }
#pragma unroll
    for (int i=0;i<4;i++){
        size_t row = (size_t)(bv*TSEQ + n0 + tm*4 + i)*DM + tn*8;
        short8 hv;
#pragma unroll
        for (int j=0;j<8;j++) hv[j] = (short)f2bf(acc[i][j]);
        *(short8*)&hB[row] = hv;
    }
}

// ---------------------------------------------------------------------------
// Per-layer weight prep: fp32 -> bf16 (hi-plane only).
// wcS = raw bf16(xpW[0..39]) padded to 48 rows.
#define PREP_ELEMS 176128
__global__ __launch_bounds__(256) void prep_layer(
    const float* __restrict__ inW, const float* __restrict__ xpW,
    const float* __restrict__ outW,
    const float* __restrict__ l1W, const float* __restrict__ l2W,
    ushort_t* __restrict__ inWh, ushort_t* __restrict__ wcS,
    ushort_t* __restrict__ outWh,
    ushort_t* __restrict__ l1Wh, ushort_t* __restrict__ l2Wh)
{
    int e = blockIdx.x*256 + threadIdx.x;
    if (e >= PREP_ELEMS) return;
    float v; ushort_t *dh; int o;
    if (e < 65536){
        v = inW[e]; dh = inWh; o = e;
    } else if (e < 77824){
        int ee = e - 65536;           // 0..12287
        int n = ee >> 8, k = ee & 255;
        v = (n < 40) ? xpW[n*256 + k] : 0.f;
        dh = wcS; o = ee;
    } else if (e < 110592){
        int ee = e - 77824; v = outW[ee]; dh = outWh; o = ee;
    } else if (e < 143360){
        int ee = e - 110592; v = l1W[ee]; dh = l1Wh; o = ee;
    } else {
        int ee = e - 143360; v = l2W[ee]; dh = l2Wh; o = ee;
    }
    dh[o] = f2bf(v);
}

// ---------------------------------------------------------------------------
// Fused in_proj GEMM + causal depthwise conv (width 4) + bias + SiLU.
// Single-plane bf16 weights (R13, validated).
__global__ __launch_bounds__(256) void gemm_inproj_conv(
    const ushort_t* __restrict__ A,
    const ushort_t* __restrict__ WH,
    const float* __restrict__ cw, const float* __restrict__ cb,
    ushort_t* __restrict__ xcB, ushort_t* __restrict__ zB)
{
    constexpr int KT = 128, NT = 64, NCHK = KT/8;
    constexpr int XSS = 68;                     // xs row stride (shorts)
    __shared__ __align__(16) char smem[259*XSS*2 + 64*5*4 + 64*4];
    ushort_t* sWh = (ushort_t*)smem;            // 8192 shorts
    ushort_t* xs  = (ushort_t*)smem;            // union with sW (after barrier)
    float* cws = (float*)(smem + 259*XSS*2);    // [c*5+k]
    float* cbs = cws + 64*5;

    int m0 = blockIdx.x*256, n0 = blockIdx.y*NT;
    bool is_x = (n0 < 256);
    int tid = threadIdx.x;
    for (int i = tid; i < NT*NCHK; i += 256) {
        int nrow = i / NCHK, c = i % NCHK;
        int cs = c ^ (nrow & 7);
        *(short8*)&sWh[nrow*KT + cs*8] = *(const short8*)&WH[(size_t)(n0+nrow)*KT + c*8];
    }
    if (is_x){
        { int c = tid >> 2, k = tid & 3; cws[c*5+k] = cw[(n0+c)*4 + k]; }
        if (tid < 64) cbs[tid] = cb[n0+tid];
    }
    __syncthreads();
    int wave = tid>>6, lane = tid&63;
    int r = lane&15, g = lane>>4;
    int mw = m0 + wave*64;
    f32x4 acc[4][4];
#pragma unroll
    for (int i=0;i<4;i++)
#pragma unroll
        for (int j=0;j<4;j++) acc[i][j] = (f32x4){0.f,0.f,0.f,0.f};
#pragma unroll
    for (int ks = 0; ks < KT/32; ks++){
        short8 ah[4];
#pragma unroll
        for (int i=0;i<4;i++){
            size_t ga = (size_t)(mw + i*16 + r)*KT + ks*32 + g*8;
            ah[i] = *(const short8*)&A[ga];
        }
        short8 wh[4];
#pragma unroll
        for (int j=0;j<4;j++){
            int nrow = j*16 + r;
            int cs = (ks*4 + g) ^ (nrow & 7);
            wh[j] = *(const short8*)&sWh[nrow*KT + cs*8];
        }
#pragma unroll
        for (int i=0;i<4;i++)
#pragma unroll
        for (int j=0;j<4;j++){
            acc[i][j] = MFMA16(ah[i], wh[j], acc[i][j]);
        }
    }
    if (!is_x){
#pragma unroll
        for (int i=0;i<4;i++)
#pragma unroll
        for (int j=0;j<4;j++)
#pragma unroll
        for (int q=0;q<4;q++){
            int mm = mw + i*16 + g*4 + q;
            int nn = n0 - 256 + j*16 + r;
            zB[(size_t)mm*DI + nn] = f2bf(acc[i][j][q]);
        }
        return;
    }
    float bacc = 0.f;
    bool bvalid = ((m0 & 1023) != 0);
    if (tid < 192 && bvalid){
        int brow = tid >> 6, bcol = tid & 63;
        const ushort_t* hrow = A  + (size_t)(m0 - 3 + brow)*KT;
        const ushort_t* wrh  = WH + (size_t)(n0 + bcol)*KT;
#pragma unroll 8
        for (int k=0;k<KT;k++)
            bacc += bf2f(hrow[k]) * bf2f(wrh[k]);
    }
    __syncthreads();   // all sW reads done -> safe to overwrite with xs
    if (tid < 192){
        int brow = tid >> 6, bcol = tid & 63;
        xs[brow*XSS + bcol] = bvalid ? f2bf(bacc) : (ushort_t)0;
    }
#pragma unroll
    for (int i=0;i<4;i++)
#pragma unroll
    for (int j=0;j<4;j++)
#pragma unroll
    for (int q=0;q<4;q++){
        int mm = mw + i*16 + g*4 + q;
        xs[(mm - m0 + 3)*XSS + j*16 + r] = f2bf(acc[i][j][q]);
    }
    __syncthreads();
    for (int p = 0; p < 64; p++){
        int idx = p*256 + tid;
        int t = idx >> 6, cl = idx & 63;
        float v = cbs[cl];
#pragma unroll
        for (int k=0;k<4;k++) v += cws[cl*5+k]*bf2f(xs[(t+k)*XSS + cl]);
        xcB[(size_t)(m0 + t)*DI + n0 + cl] = f2bf(silu_f(v));
    }
}

// ---------------------------------------------------------------------------
// x_proj, rank-8 factored + inline scan pass 1, 512 threads (R17).
// bf16 state planes in the coalesced layout (R18). Fast softplus (R19).
__global__ __launch_bounds__(512) void gemm_xproj(
    const ushort_t* __restrict__ A,        // xcB [M][256] bf16
    const ushort_t* __restrict__ WS,       // wcS [48][256] bf16
    const float* __restrict__ dtw,         // dt_proj_w [256][8] fp32
    const float* __restrict__ bias,        // dtB [256]
    const float* __restrict__ Alog,        // [256][16]
    unsigned int* __restrict__ duB, float* __restrict__ xbcF,
    ushort_t* __restrict__ hloc, float* __restrict__ sd)
{
    constexpr int KT = 256, NT = 48, MT = 64;
    constexpr int NCHK = KT/8;              // 32
    __shared__ ushort_t sW[NT*KT];          // 24576 B
    __shared__ __align__(16) float dtS[MT][8];   // 2048 B
    __shared__ __align__(16) float BsL[MT][16];  // 4096 B
    int m0 = blockIdx.x*MT;
    int tid = threadIdx.x;
    for (int i = tid; i < NT*NCHK; i += 512) {
        int nrow = i / NCHK, c = i % NCHK;
        int cs = c ^ (nrow & 7);
        *(short8*)&sW[nrow*KT + cs*8] = *(const short8*)&WS[(size_t)nrow*KT + c*8];
    }
    __syncthreads();
    // Phase 1: 8 waves = m-tile (wave&3) x n-part (wave>>2).
    {
        int wave = tid>>6, lane = tid&63;
        int r = lane&15, g = lane>>4;
        int mi = wave & 3, part = wave >> 2;
        int NJ = (part == 0) ? 2 : 1;
        int mw = m0 + mi*16;
        f32x4 acc[2];
#pragma unroll
        for (int j=0;j<2;j++) acc[j] = (f32x4){0.f,0.f,0.f,0.f};
#pragma unroll
        for (int ks = 0; ks < KT/32; ks++){
            short8 ah = *(const short8*)&A[(size_t)(mw + r)*KT + ks*32 + g*8];
#pragma unroll
            for (int j=0;j<2;j++){
                if (j < NJ){
                    int nrow = (part*2 + j)*16 + r;
                    int cs = (ks*4 + g) ^ (nrow & 7);
                    short8 wh = *(const short8*)&sW[nrow*KT + cs*8];
                    acc[j] = MFMA16(ah, wh, acc[j]);
                }
            }
        }
        // Epilogue: dt -> LDS, B -> LDS + xbcF, C -> xbcF
#pragma unroll
        for (int j=0;j<2;j++){
            if (j < NJ){
                int nn = (part*2 + j)*16 + r;
#pragma unroll
                for (int q=0;q<4;q++){
                    int mm = mw + g*4 + q;
                    float v = acc[j][q];
                    if (nn < 8){
                        dtS[mm - m0][nn] = v;
                    } else if (nn < 40){
                        xbcF[(size_t)mm*32 + (nn - 8)] = v;
                        if (nn < 24) BsL[mm - m0][nn - 8] = v;
                    }
                }
            }
        }
    }
    __syncthreads();
    // Phase 2: delta expansion + pack, fused chunk-local scan (h0 = 0).
    {
        int half = tid >> 8;
        int d = tid & 255;
        float4 dw0 = *(const float4*)&dtw[d*8];
        float4 dw1 = *(const float4*)&dtw[d*8 + 4];
        float bd = bias[d];
        float A0; bool structured;
        {
            float4 a0 = *(const float4*)&Alog[d*16];
            float4 a1 = *(const float4*)&Alog[d*16+4];
            float4 a2 = *(const float4*)&Alog[d*16+8];
            float4 a3 = *(const float4*)&Alog[d*16+12];
            float tmp[16] = {a0.x,a0.y,a0.z,a0.w,a1.x,a1.y,a1.z,a1.w,
                             a2.x,a2.y,a2.z,a2.w,a3.x,a3.y,a3.z,a3.w};
            float At[16];
#pragma unroll
            for (int s=0;s<16;s++) At[s] = -__expf(tmp[s]);
            structured = a_structured(At);
            A0 = At[0];
        }
        int b  = m0 >> 10;            // TSEQ = 1024
        int c  = ((m0 & 1023) >> 5) + half;
        float h[16];
#pragma unroll
        for (int s=0;s<16;s++) h[s] = 0.f;
        float sdv = 0.f;
#pragma unroll
        for (int t0 = 0; t0 < CSZ; t0 += 8){
            ushort_t uu[8];
#pragma unroll
            for (int k=0;k<8;k++)
                uu[k] = A[(size_t)(m0 + half*CSZ + t0 + k)*KT + d];
#pragma unroll
            for (int k=0;k<8;k++){
                int t = half*CSZ + t0 + k;
                const float* dt8 = dtS[t];
                float4 a0 = *(const float4*)&dt8[0];
                float4 a1 = *(const float4*)&dt8[4];
                float v = bd + a0.x*dw0.x + a0.y*dw0.y + a0.z*dw0.z + a0.w*dw0.w
                             + a1.x*dw1.x + a1.y*dw1.y + a1.z*dw1.z + a1.w*dw1.w;
                float delta = softplus_f(v);
                ushort_t dh = f2bf(delta);
                duB[(size_t)(m0 + t)*KT + d] =
                    ((unsigned int)dh << 16) | (unsigned int)uu[k];
                // inline pass1 (rounded values = what the scan consumes)
                float dlt = bf2f(dh);
                float uv  = bf2f(uu[k]);
                sdv += dlt;
                float duv = dlt*uv;
                const float4* Bp = (const float4*)&BsL[t][0];
                if (structured){
                    float p  = __expf(dlt*A0);
                    float p2 = p*p, p4 = p2*p2;
                    float f1 = p, f2 = p2, f3 = p2*p, f4 = p4;
#pragma unroll
                    for (int q=0;q<4;q++){
                        float4 bq = Bp[q];
                        h[4*q+0] = f1*h[4*q+0] + duv*bq.x;
                        h[4*q+1] = f2*h[4*q+1] + duv*bq.y;
                        h[4*q+2] = f3*h[4*q+2] + duv*bq.z;
                        h[4*q+3] = f4*h[4*q+3] + duv*bq.w;
                        if (q < 3){ f1 *= p4; f2 *= p4; f3 *= p4; f4 *= p4; }
                    }
                } else {
#pragma unroll
                    for (int q=0;q<4;q++){
                        float4 aq = *(const float4*)&Alog[d*16 + 4*q];
                        float4 bq = Bp[q];
                        h[4*q+0] = __expf(-dlt*__expf(aq.x))*h[4*q+0] + duv*bq.x;
                        h[4*q+1] = __expf(-dlt*__expf(aq.y))*h[4*q+1] + duv*bq.y;
                        h[4*q+2] = __expf(-dlt*__expf(aq.z))*h[4*q+2] + duv*bq.z;
                        h[4*q+3] = __expf(-dlt*__expf(aq.w))*h[4*q+3] + duv*bq.w;
                    }
                }
            }
        }
#pragma unroll
        for (int s=0;s<16;s++)
            hloc[((size_t)((b*NCH + c)*16 + s))*DI + d] = f2bf(h[s]);
        sd[(b*NCH + c)*DI + d] = sdv;
    }
}

// ---------------------------------------------------------------------------
// Prefix-combine over chunks (thread = (b,s,d)) — coalesced layout, bf16
// states (R18/R20 form).
__global__ __launch_bounds__(256) void scan_combine(
    const ushort_t* __restrict__ hloc, const float* __restrict__ sd,
    const float* __restrict__ Alog, ushort_t* __restrict__ hstart)
{
    int b = blockIdx.x, s = blockIdx.y;
    int d = threadIdx.x;
    float A = -__expf(Alog[d*16+s]);
    float hs = 0.f;
    for (int c = 0; c < NCH; c++){
        size_t base = ((size_t)((b*NCH + c)*16 + s))*DI + d;
        hstart[base] = f2bf(hs);
        float sdp = sd[(b*NCH + c)*DI + d];
        hs = __expf(sdp*A)*hs + bf2f(hloc[base]);
    }
}

// ---------------------------------------------------------------------------
// Fused scan pass 2 + out_proj + FFN (fast gelu) for a 32-token chunk.
// Phase A: TWO loads per token (packed du 4B + z 2B), depth-8 double-buffer.
// h-init from bf16 hstart (same coalesced layout).
// Phase B: SINGLE-plane bf16 weights (R12, validated).
__global__ __launch_bounds__(256,4) void scan_fused(
    const unsigned int* __restrict__ duB, const float* __restrict__ xbcF,
    const ushort_t* __restrict__ zB,
    const float* __restrict__ Alog, const float* __restrict__ Dp,
    const ushort_t* __restrict__ hstart,
    const ushort_t* __restrict__ oWh,
    const ushort_t* __restrict__ w1h,
    const float* __restrict__ b1,
    const ushort_t* __restrict__ w2h,
    const float* __restrict__ b2,
    ushort_t* __restrict__ hB)
{
    constexpr int YS = DI + 8;    // 264 shorts
    constexpr int OS = DM + 8;    // 136 shorts
    __shared__ __align__(16) ushort_t smem[CSZ*YS + CSZ*OS];   // 25600 B
    ushort_t* yB = smem;                      // [t*YS + d]
    ushort_t* oB = smem + CSZ*YS;             // [t*OS + n]
    float*    Bs = (float*)(smem + CSZ*YS);   // union with oB
    float*    Cs = Bs + CSZ*16;

    int b = blockIdx.x, c = blockIdx.y;
    int tid = threadIdx.x;
    int mbase = b*TSEQ + c*CSZ;
    for (int i = tid; i < CSZ*32; i += 256) {
        int t = i >> 5, s2 = i & 31;
        float v = xbcF[(size_t)(mbase+t)*32 + s2];
        if (s2 < 16) Bs[t*16+s2] = v; else Cs[t*16+s2-16] = v;
    }
    // ---- Phase A: scan
    {
        int d = tid;
        // group-0 register prefetch: overlaps barrier + A/hstart setup
        unsigned int du[2][8]; ushort_t zz[2][8];
#pragma unroll
        for (int k=0;k<8;k++){
            size_t m = (size_t)(mbase+k);
            du[0][k] = duB[m*DI + d];
            zz[0][k] = zB[m*DI + d];
        }
        float A0; bool structured;
        {
            float4 a0 = *(const float4*)&Alog[d*16];
            float4 a1 = *(const float4*)&Alog[d*16+4];
            float4 a2 = *(const float4*)&Alog[d*16+8];
            float4 a3 = *(const float4*)&Alog[d*16+12];
            float tmp[16] = {a0.x,a0.y,a0.z,a0.w,a1.x,a1.y,a1.z,a1.w,
                             a2.x,a2.y,a2.z,a2.w,a3.x,a3.y,a3.z,a3.w};
            float At[16];
#pragma unroll
            for (int s=0;s<16;s++) At[s] = -__expf(tmp[s]);
            structured = a_structured(At);
            A0 = At[0];
        }
        float h[16];
#pragma unroll
        for (int s=0;s<16;s++)
            h[s] = bf2f(hstart[((size_t)((b*NCH + c)*16 + s))*DI + d]);
        float Dd = Dp[d];
        __syncthreads();
        if (structured){
#pragma unroll
            for (int t0i = 0; t0i < CSZ/8; t0i++){
                int cur = t0i & 1, nxt = cur ^ 1;   // static after unroll
                if (t0i < CSZ/8 - 1){
#pragma unroll
                    for (int k=0;k<8;k++){
                        size_t m = (size_t)(mbase + (t0i+1)*8 + k);
                        du[nxt][k] = duB[m*DI + d];
                        zz[nxt][k] = zB[m*DI + d];
                    }
                }
#pragma unroll
                for (int k=0;k<8;k++){
                    int t = t0i*8 + k;
                    unsigned int pk_ = du[cur][k];
                    float dlt = bf2f((ushort_t)(pk_ >> 16));
                    float uv  = bf2f((ushort_t)(pk_ & 0xffffu));
                    float duv = dlt*uv;
                    float p  = __expf(dlt*A0);
                    float p2 = p*p, p4 = p2*p2;
                    float f1 = p, f2 = p2, f3 = p2*p, f4 = p4;
                    const float4* Bp = (const float4*)&Bs[t*16];
                    const float4* Cp = (const float4*)&Cs[t*16];
                    float y0=0.f, y1=0.f, y2=0.f, y3=0.f;
#pragma unroll
                    for (int q=0;q<4;q++){
                        float4 bq = Bp[q];
                        float4 cq = Cp[q];
                        h[4*q+0] = f1*h[4*q+0] + duv*bq.x; y0 += h[4*q+0]*cq.x;
                        h[4*q+1] = f2*h[4*q+1] + duv*bq.y; y1 += h[4*q+1]*cq.y;
                        h[4*q+2] = f3*h[4*q+2] + duv*bq.z; y2 += h[4*q+2]*cq.z;
                        h[4*q+3] = f4*h[4*q+3] + duv*bq.w; y3 += h[4*q+3]*cq.w;
                        if (q < 3){ f1 *= p4; f2 *= p4; f3 *= p4; f4 *= p4; }
                    }
                    float y = (y0+y1)+(y2+y3);
                    yB[t*YS+d] = f2bf((y + uv*Dd) * silu_f(bf2f(zz[cur][k])));
                }
            }
        } else {
            // cold fallback: general A (reloaded from global per 4-state group)
            for (int t = 0; t < CSZ; t++){
                size_t m = (size_t)(mbase+t);
                unsigned int pk_ = duB[m*DI + d];
                float dlt = bf2f((ushort_t)(pk_ >> 16));
                float uv  = bf2f((ushort_t)(pk_ & 0xffffu));
                float zv  = bf2f(zB[m*DI + d]);
                float duv = dlt*uv;
                float y0=0.f, y1=0.f, y2=0.f, y3=0.f;
#pragma unroll
                for (int q=0;q<4;q++){
                    float4 aq = *(const float4*)&Alog[d*16 + 4*q];
                    float4 bq = *(const float4*)&Bs[t*16 + 4*q];
                    float4 cq = *(const float4*)&Cs[t*16 + 4*q];
                    h[4*q+0] = __expf(-dlt*__expf(aq.x))*h[4*q+0] + duv*bq.x; y0 += h[4*q+0]*cq.x;
                    h[4*q+1] = __expf(-dlt*__expf(aq.y))*h[4*q+1] + duv*bq.y; y1 += h[4*q+1]*cq.y;
                    h[4*q+2] = __expf(-dlt*__expf(aq.z))*h[4*q+2] + duv*bq.z; y2 += h[4*q+2]*cq.z;
                    h[4*q+3] = __expf(-dlt*__expf(aq.w))*h[4*q+3] + duv*bq.w; y3 += h[4*q+3]*cq.w;
                }
                float y = (y0+y1)+(y2+y3);
                yB[t*YS+d] = f2bf((y + uv*Dd) * silu_f(zv));
            }
        }
    }
    __syncthreads();   // yB done; Bs/Cs dead -> region2 reusable as oB
    // ---- Phase B (single-plane bf16 weights)
    int wave = tid>>6, lane = tid&63;
    int r = lane&15, g = lane>>4;
    // Stage 1: o[32][128] = y @ oW^T  (K=256)
    {
        f32x4 s1[2][2];
#pragma unroll
        for (int i=0;i<2;i++)
#pragma unroll
            for (int j=0;j<2;j++) s1[i][j] = (f32x4){0.f,0.f,0.f,0.f};
#pragma unroll
        for (int ks=0;ks<8;ks++){
            short8 ya[2];
#pragma unroll
            for (int i=0;i<2;i++)
                ya[i] = *(const short8*)&yB[(i*16+r)*YS + ks*32 + g*8];
            short8 wh_[2];
#pragma unroll
            for (int j=0;j<2;j++){
                size_t wa = (size_t)(wave*32 + j*16 + r)*256 + ks*32 + g*8;
                wh_[j] = *(const short8*)&oWh[wa];
            }
#pragma unroll
            for (int i=0;i<2;i++)
#pragma unroll
            for (int j=0;j<2;j++){
                s1[i][j] = MFMA16(ya[i], wh_[j], s1[i][j]);
            }
        }
#pragma unroll
        for (int i=0;i<2;i++)
#pragma unroll
        for (int j=0;j<2;j++)
#pragma unroll
        for (int q=0;q<4;q++){
            int t = i*16 + g*4 + q;
            int n = wave*32 + j*16 + r;
            oB[t*OS+n] = f2bf(s1[i][j][q]);
        }
    }
    __syncthreads();   // oB ready; yB reads done
    // Stage 2: f[32][256] = gelu(o @ w1^T + b1)  (K=128), into yB
    {
        f32x4 s2[2][4];
#pragma unroll
        for (int i=0;i<2;i++)
#pragma unroll
            for (int j=0;j<4;j++) s2[i][j] = (f32x4){0.f,0.f,0.f,0.f};
#pragma unroll
        for (int ks=0;ks<4;ks++){
            short8 oa[2];
#pragma unroll
            for (int i=0;i<2;i++)
                oa[i] = *(const short8*)&oB[(i*16+r)*OS + ks*32 + g*8];
            short8 wh_[4];
#pragma unroll
            for (int j=0;j<4;j++){
                size_t wa = (size_t)(wave*64 + j*16 + r)*128 + ks*32 + g*8;
                wh_[j] = *(const short8*)&w1h[wa];
            }
#pragma unroll
            for (int i=0;i<2;i++)
#pragma unroll
            for (int j=0;j<4;j++){
                s2[i][j] = MFMA16(oa[i], wh_[j], s2[i][j]);
            }
        }
#pragma unroll
        for (int i=0;i<2;i++)
#pragma unroll
        for (int j=0;j<4;j++)
#pragma unroll
        for (int q=0;q<4;q++){
            int t = i*16 + g*4 + q;
            int n = wave*64 + j*16 + r;
            yB[t*YS+n] = f2bf(gelu_f(s2[i][j][q] + b1[n]));
        }
    }
    __syncthreads();   // f (in yB) done
    // Stage 3: hnew[32][128] = f @ w2^T + b2  (K=256) -> global plane
    {
        f32x4 s3[2][2];
#pragma unroll
        for (int i=0;i<2;i++)
#pragma unroll
            for (int j=0;j<2;j++) s3[i][j] = (f32x4){0.f,0.f,0.f,0.f};
#pragma unroll
        for (int ks=0;ks<8;ks++){
            short8 fa[2];
#pragma unroll
            for (int i=0;i<2;i++)
                fa[i] = *(const short8*)&yB[(i*16+r)*YS + ks*32 + g*8];
            short8 wh_[2];
#pragma unroll
            for (int j=0;j<2;j++){
                size_t wa = (size_t)(wave*32 + j*16 + r)*256 + ks*32 + g*8;
                wh_[j] = *(const short8*)&w2h[wa];
            }
#pragma unroll
            for (int i=0;i<2;i++)
#pragma unroll
            for (int j=0;j<2;j++){
                s3[i][j] = MFMA16(fa[i], wh_[j], s3[i][j]);
            }
        }
#pragma unroll
        for (int i=0;i<2;i++)
#pragma unroll
        for (int j=0;j<2;j++)
#pragma unroll
        for (int q=0;q<4;q++){
            int t = i*16 + g*4 + q;
            int n = wave*32 + j*16 + r;
            hB[(size_t)(mbase + t)*DM + n] = f2bf(s3[i][j][q] + b2[n]);
        }
    }
}

// ---------------------------------------------------------------------------
// Final transpose: out[bv, d, n] = h[bv*1024+n, d]
__global__ __launch_bounds__(256) void final_transpose(
    const ushort_t* __restrict__ hB, float* __restrict__ out)
{
    int n0 = blockIdx.x*32, d0 = blockIdx.y*32, bv = blockIdx.z;
    __shared__ float ts[32][33];
    int tid = threadIdx.x;
    int c = tid & 31, r0 = tid >> 5;
    for (int rr = r0; rr < 32; rr += 8)
        ts[rr][c] = bf2f(hB[(size_t)(bv*TSEQ + n0 + rr)*DM + d0 + c]);
    __syncthreads();
    for (int rr = r0; rr < 32; rr += 8)
        out[(size_t)(bv*DM + d0 + rr)*TSEQ + n0 + c] = ts[c][rr];
}

// ---------------------------------------------------------------------------
extern "C" void kernel_launch(void* const* d_in, const int* in_sizes, int n_in,
                              void* d_out, int out_size, void* d_ws, size_t ws_size,
                              hipStream_t stream)
{
    const float* x     = (const float*)d_in[0];
    const float* Wp    = (const float*)d_in[1];
    const float* Wpb   = (const float*)d_in[2];
    const float* inW   = (const float*)d_in[3];
    const float* convW = (const float*)d_in[4];
    const float* convB = (const float*)d_in[5];
    const float* xpW   = (const float*)d_in[6];
    const float* dtW   = (const float*)d_in[7];
    const float* dtB   = (const float*)d_in[8];
    const float* Alog  = (const float*)d_in[9];
    const float* Dp    = (const float*)d_in[10];
    const float* outW  = (const float*)d_in[11];
    const float* l1W   = (const float*)d_in[12];
    const float* l1B   = (const float*)d_in[13];
    const float* l2W   = (const float*)d_in[14];
    const float* l2B   = (const float*)d_in[15];
    float* out = (float*)d_out;

    char* base = (char*)d_ws;
    size_t off = 0;
    auto alloc = [&](size_t bytes) { char* p = base + off; off += (bytes + 255) & ~(size_t)255; return p; };

    const size_t P128 = (size_t)MTOK*DM*2;     // [M][128] bf16 plane
    const size_t P256 = (size_t)MTOK*DI*2;     // [M][256] bf16 plane

    ushort_t* hB  = (ushort_t*)alloc(P128);
    unsigned int* duB = (unsigned int*)alloc((size_t)MTOK*DI*4);  // delta|u packed
    float* xbcF   = (float*)alloc((size_t)MTOK*32*4);             // B|C fp32
    ushort_t* zB  = (ushort_t*)alloc(P256);
    ushort_t* xcB = (ushort_t*)alloc(P256);
    ushort_t* hloc   = (ushort_t*)alloc((size_t)BSEQ*NCH*DS*DI*2);  // bf16 states
    ushort_t* hstart = (ushort_t*)alloc((size_t)BSEQ*NCH*DS*DI*2);  // bf16 states
    float* sd     = (float*)alloc((size_t)BSEQ*NCH*DI*4);
    ushort_t* inWh  = (ushort_t*)alloc((size_t)512*128*2);
    ushort_t* wcS   = (ushort_t*)alloc((size_t)48*256*2);
    ushort_t* outWh = (ushort_t*)alloc((size_t)128*256*2);
    ushort_t* l1Wh  = (ushort_t*)alloc((size_t)256*128*2);
    ushort_t* l2Wh  = (ushort_t*)alloc((size_t)128*256*2);

    patch_embed<<<dim3(32,16), 256, 0, stream>>>(x, Wp, Wpb, hB);

    for (int L = 0; L < L_LAYERS; L++) {
        const float* inW_l   = inW   + (size_t)L*2*DI*DM;
        const float* convW_l = convW + (size_t)L*DI*4;
        const float* convB_l = convB + (size_t)L*DI;
        const float* xpW_l   = xpW   + (size_t)L*(DTR+2*DS)*DI;
        const float* dtW_l   = dtW   + (size_t)L*DI*DTR;
        const float* dtB_l   = dtB   + (size_t)L*DI;
        const float* Alog_l  = Alog  + (size_t)L*DI*DS;
        const float* Dp_l    = Dp    + (size_t)L*DI;
        const float* outW_l  = outW  + (size_t)L*DM*DI;
        const float* l1W_l   = l1W   + (size_t)L*DFF*DM;
        const float* l1B_l   = l1B   + (size_t)L*DFF;
        const float* l2W_l   = l2W   + (size_t)L*DM*DFF;
        const float* l2B_l   = l2B   + (size_t)L*DM;

        prep_layer<<<(PREP_ELEMS+255)/256, 256, 0, stream>>>(
            inW_l, xpW_l, outW_l, l1W_l, l2W_l,
            inWh, wcS, outWh, l1Wh, l2Wh);

        gemm_inproj_conv<<<dim3(MTOK/256, 8), 256, 0, stream>>>(
            hB, inWh, convW_l, convB_l, xcB, zB);
        gemm_xproj<<<dim3(MTOK/64), 512, 0, stream>>>(
            xcB, wcS, dtW_l, dtB_l, Alog_l, duB, xbcF, hloc, sd);
        scan_combine<<<dim3(BSEQ, DS), 256, 0, stream>>>(
            hloc, sd, Alog_l, hstart);
        scan_fused<<<dim3(BSEQ, NCH), 256, 0, stream>>>(
            duB, xbcF, zB, Alog_l, Dp_l, hstart,
            outWh, l1Wh, l1B_l, l2Wh, l2B_l, hB);
    }

    final_transpose<<<dim3(TSEQ/32, DM/32, BSEQ), 256, 0, stream>>>(hB, out);
}

// Round 22
// 309.128 us; speedup vs baseline: 1.3361x; 1.0102x over previous
//
#include <hip/hip_runtime.h>
#include <math.h>

// Problem constants
#define L_LAYERS 2
#define DM   128
#define DI   256
#define DS   16
#define DTR  8
#define DFF  256
#define PLEN 16
#define BSEQ 32
#define TSEQ 1024
#define MTOK (BSEQ*TSEQ)   // 32768
#define NCH  32            // scan chunks
#define CSZ  32            // TSEQ/NCH

typedef unsigned short ushort_t;
typedef __attribute__((ext_vector_type(8))) short short8;
typedef __attribute__((ext_vector_type(4))) float f32x4;
typedef __attribute__((ext_vector_type(2))) float f32x2;
#define MFMA16(a,b,c) __builtin_amdgcn_mfma_f32_16x16x32_bf16(a,b,c,0,0,0)

__device__ __forceinline__ float silu_f(float x){ return x / (1.f + __expf(-x)); }
// Fast gelu (R21): tanh-form with hardware exp (neutral vs erff, kept).
__device__ __forceinline__ float gelu_f(float x){
    float x3 = x*x*x;
    float t = __expf(1.5957691216f*x + 0.0713548162f*x3);
    return x * __fdividef(t, t + 1.f);
}
// Fast softplus (R19/R20, validated: -44us vs library log1pf).
__device__ __forceinline__ float softplus_f(float x){
    return (x > 20.f) ? x : __logf(1.f + __expf(x));
}

__device__ __forceinline__ ushort_t f2bf(float f){
    unsigned int u = __float_as_uint(f);
    u += 0x7fffu + ((u >> 16) & 1u);
    return (ushort_t)(u >> 16);
}
__device__ __forceinline__ float bf2f(ushort_t h){
    return __uint_as_float(((unsigned int)h) << 16);
}

// Check A[s] ~= A[0]*(s+1) (true for the reference A_log = log(1..16) tiled).
__device__ __forceinline__ bool a_structured(const float* A){
    bool ok = (A[0] < 0.f);
#pragma unroll
    for (int s=1;s<16;s++){
        float r = A[s]/A[0];
        ok = ok && (fabsf(r - (float)(s+1)) <= 1e-3f);
    }
    return ok;
}

// ---------------------------------------------------------------------------
// Patch embedding -> h (single bf16 plane)
__global__ __launch_bounds__(256) void patch_embed(
    const float* __restrict__ x, const float* __restrict__ Wp,
    const float* __restrict__ bp, ushort_t* __restrict__ hB)
{
    int bv = blockIdx.x, n0 = blockIdx.y * 64;
    __shared__ float xs[PLEN][64];
    __shared__ float ws[PLEN][DM];
    __shared__ float bs[DM];
    int tid = threadIdx.x;
    {
        int c = tid & 63, r0 = tid >> 6;
        for (int p = r0; p < PLEN; p += 4)
            xs[p][c] = x[bv*(PLEN*TSEQ) + p*TSEQ + n0 + c];
    }
    for (int i = tid; i < DM*PLEN; i += 256) {
        int d = i >> 4, p = i & 15;
        ws[p][d] = Wp[i];
    }
    if (tid < DM) bs[tid] = bp[tid];
    __syncthreads();
    int tm = tid & 15;
    int tn = tid >> 4;
    float acc[4][8];
#pragma unroll
    for (int i=0;i<4;i++)
#pragma unroll
        for (int j=0;j<8;j++) acc[i][j] = bs[tn*8+j];
#pragma unroll
    for (int p=0;p<PLEN;p++) {
        float4 a = *(const float4*)&xs[p][tm*4];
        float4 w0 = *(const float4*)&ws[p][tn*8];
        float4 w1 = *(const float4*)&ws[p][tn*8+4];
        const float* ap = (const float*)&a;
        const float* wp0 = (const float*)&w0;
        const float* wp1 = (const float*)&w1;
#pragma unroll
        for (int i=0;i<4;i++){
#pragma unroll
            for (int j=0;j<4;j++){
                acc[i][j]   += ap[i]*wp0[j];
                acc[i][j+4] += ap[i]*wp1[j];
            }
        }
    }
#pragma unroll
    for (int i=0;i<4;i++){
        size_t row = (size_t)(bv*TSEQ + n0 + tm*4 + i)*DM + tn*8;
        short8 hv;
#pragma unroll
        for (int j=0;j<8;j++) hv[j] = (short)f2bf(acc[i][j]);
        *(short8*)&hB[row] = hv;
    }
}

// ---------------------------------------------------------------------------
// Per-layer weight prep: fp32 -> bf16 (hi-plane only).
// wcS = raw bf16(xpW[0..39]) padded to 48 rows.
#define PREP_ELEMS 176128
__global__ __launch_bounds__(256) void prep_layer(
    const float* __restrict__ inW, const float* __restrict__ xpW,
    const float* __restrict__ outW,
    const float* __restrict__ l1W, const float* __restrict__ l2W,
    ushort_t* __restrict__ inWh, ushort_t* __restrict__ wcS,
    ushort_t* __restrict__ outWh,
    ushort_t* __restrict__ l1Wh, ushort_t* __restrict__ l2Wh)
{
    int e = blockIdx.x*256 + threadIdx.x;
    if (e >= PREP_ELEMS) return;
    float v; ushort_t *dh; int o;
    if (e < 65536){
        v = inW[e]; dh = inWh; o = e;
    } else if (e < 77824){
        int ee = e - 65536;           // 0..12287
        int n = ee >> 8, k = ee & 255;
        v = (n < 40) ? xpW[n*256 + k] : 0.f;
        dh = wcS; o = ee;
    } else if (e < 110592){
        int ee = e - 77824; v = outW[ee]; dh = outWh; o = ee;
    } else if (e < 143360){
        int ee = e - 110592; v = l1W[ee]; dh = l1Wh; o = ee;
    } else {
        int ee = e - 143360; v = l2W[ee]; dh = l2Wh; o = ee;
    }
    dh[o] = f2bf(v);
}

// ---------------------------------------------------------------------------
// Fused in_proj GEMM + causal depthwise conv (width 4) + bias + SiLU.
// Single-plane bf16 weights (R13, validated).
__global__ __launch_bounds__(256) void gemm_inproj_conv(
    const ushort_t* __restrict__ A,
    const ushort_t* __restrict__ WH,
    const float* __restrict__ cw, const float* __restrict__ cb,
    ushort_t* __restrict__ xcB, ushort_t* __restrict__ zB)
{
    constexpr int KT = 128, NT = 64, NCHK = KT/8;
    constexpr int XSS = 68;                     // xs row stride (shorts)
    __shared__ __align__(16) char smem[259*XSS*2 + 64*5*4 + 64*4];
    ushort_t* sWh = (ushort_t*)smem;            // 8192 shorts
    ushort_t* xs  = (ushort_t*)smem;            // union with sW (after barrier)
    float* cws = (float*)(smem + 259*XSS*2);    // [c*5+k]
    float* cbs = cws + 64*5;

    int m0 = blockIdx.x*256, n0 = blockIdx.y*NT;
    bool is_x = (n0 < 256);
    int tid = threadIdx.x;
    for (int i = tid; i < NT*NCHK; i += 256) {
        int nrow = i / NCHK, c = i % NCHK;
        int cs = c ^ (nrow & 7);
        *(short8*)&sWh[nrow*KT + cs*8] = *(const short8*)&WH[(size_t)(n0+nrow)*KT + c*8];
    }
    if (is_x){
        { int c = tid >> 2, k = tid & 3; cws[c*5+k] = cw[(n0+c)*4 + k]; }
        if (tid < 64) cbs[tid] = cb[n0+tid];
    }
    __syncthreads();
    int wave = tid>>6, lane = tid&63;
    int r = lane&15, g = lane>>4;
    int mw = m0 + wave*64;
    f32x4 acc[4][4];
#pragma unroll
    for (int i=0;i<4;i++)
#pragma unroll
        for (int j=0;j<4;j++) acc[i][j] = (f32x4){0.f,0.f,0.f,0.f};
#pragma unroll
    for (int ks = 0; ks < KT/32; ks++){
        short8 ah[4];
#pragma unroll
        for (int i=0;i<4;i++){
            size_t ga = (size_t)(mw + i*16 + r)*KT + ks*32 + g*8;
            ah[i] = *(const short8*)&A[ga];
        }
        short8 wh[4];
#pragma unroll
        for (int j=0;j<4;j++){
            int nrow = j*16 + r;
            int cs = (ks*4 + g) ^ (nrow & 7);
            wh[j] = *(const short8*)&sWh[nrow*KT + cs*8];
        }
#pragma unroll
        for (int i=0;i<4;i++)
#pragma unroll
        for (int j=0;j<4;j++){
            acc[i][j] = MFMA16(ah[i], wh[j], acc[i][j]);
        }
    }
    if (!is_x){
#pragma unroll
        for (int i=0;i<4;i++)
#pragma unroll
        for (int j=0;j<4;j++)
#pragma unroll
        for (int q=0;q<4;q++){
            int mm = mw + i*16 + g*4 + q;
            int nn = n0 - 256 + j*16 + r;
            zB[(size_t)mm*DI + nn] = f2bf(acc[i][j][q]);
        }
        return;
    }
    float bacc = 0.f;
    bool bvalid = ((m0 & 1023) != 0);
    if (tid < 192 && bvalid){
        int brow = tid >> 6, bcol = tid & 63;
        const ushort_t* hrow = A  + (size_t)(m0 - 3 + brow)*KT;
        const ushort_t* wrh  = WH + (size_t)(n0 + bcol)*KT;
#pragma unroll 8
        for (int k=0;k<KT;k++)
            bacc += bf2f(hrow[k]) * bf2f(wrh[k]);
    }
    __syncthreads();   // all sW reads done -> safe to overwrite with xs
    if (tid < 192){
        int brow = tid >> 6, bcol = tid & 63;
        xs[brow*XSS + bcol] = bvalid ? f2bf(bacc) : (ushort_t)0;
    }
#pragma unroll
    for (int i=0;i<4;i++)
#pragma unroll
    for (int j=0;j<4;j++)
#pragma unroll
    for (int q=0;q<4;q++){
        int mm = mw + i*16 + g*4 + q;
        xs[(mm - m0 + 3)*XSS + j*16 + r] = f2bf(acc[i][j][q]);
    }
    __syncthreads();
    for (int p = 0; p < 64; p++){
        int idx = p*256 + tid;
        int t = idx >> 6, cl = idx & 63;
        float v = cbs[cl];
#pragma unroll
        for (int k=0;k<4;k++) v += cws[cl*5+k]*bf2f(xs[(t+k)*XSS + cl]);
        xcB[(size_t)(m0 + t)*DI + n0 + cl] = f2bf(silu_f(v));
    }
}

// ---------------------------------------------------------------------------
// x_proj, rank-8 factored + inline scan pass 1, 512 threads (R17).
// bf16 state planes (R18), fast softplus (R19).
// R22: packed-fp32 h-recurrence — f32x2 state so LLVM can select
// v_pk_fma_f32/v_pk_mul_f32 (2 fp32/instr). Bit-identical math (same ops,
// same order, just lane-paired).
__global__ __launch_bounds__(512) void gemm_xproj(
    const ushort_t* __restrict__ A,        // xcB [M][256] bf16
    const ushort_t* __restrict__ WS,       // wcS [48][256] bf16
    const float* __restrict__ dtw,         // dt_proj_w [256][8] fp32
    const float* __restrict__ bias,        // dtB [256]
    const float* __restrict__ Alog,        // [256][16]
    unsigned int* __restrict__ duB, float* __restrict__ xbcF,
    ushort_t* __restrict__ hloc, float* __restrict__ sd)
{
    constexpr int KT = 256, NT = 48, MT = 64;
    constexpr int NCHK = KT/8;              // 32
    __shared__ ushort_t sW[NT*KT];          // 24576 B
    __shared__ __align__(16) float dtS[MT][8];   // 2048 B
    __shared__ __align__(16) float BsL[MT][16];  // 4096 B
    int m0 = blockIdx.x*MT;
    int tid = threadIdx.x;
    for (int i = tid; i < NT*NCHK; i += 512) {
        int nrow = i / NCHK, c = i % NCHK;
        int cs = c ^ (nrow & 7);
        *(short8*)&sW[nrow*KT + cs*8] = *(const short8*)&WS[(size_t)nrow*KT + c*8];
    }
    __syncthreads();
    // Phase 1: 8 waves = m-tile (wave&3) x n-part (wave>>2).
    {
        int wave = tid>>6, lane = tid&63;
        int r = lane&15, g = lane>>4;
        int mi = wave & 3, part = wave >> 2;
        int NJ = (part == 0) ? 2 : 1;
        int mw = m0 + mi*16;
        f32x4 acc[2];
#pragma unroll
        for (int j=0;j<2;j++) acc[j] = (f32x4){0.f,0.f,0.f,0.f};
#pragma unroll
        for (int ks = 0; ks < KT/32; ks++){
            short8 ah = *(const short8*)&A[(size_t)(mw + r)*KT + ks*32 + g*8];
#pragma unroll
            for (int j=0;j<2;j++){
                if (j < NJ){
                    int nrow = (part*2 + j)*16 + r;
                    int cs = (ks*4 + g) ^ (nrow & 7);
                    short8 wh = *(const short8*)&sW[nrow*KT + cs*8];
                    acc[j] = MFMA16(ah, wh, acc[j]);
                }
            }
        }
        // Epilogue: dt -> LDS, B -> LDS + xbcF, C -> xbcF
#pragma unroll
        for (int j=0;j<2;j++){
            if (j < NJ){
                int nn = (part*2 + j)*16 + r;
#pragma unroll
                for (int q=0;q<4;q++){
                    int mm = mw + g*4 + q;
                    float v = acc[j][q];
                    if (nn < 8){
                        dtS[mm - m0][nn] = v;
                    } else if (nn < 40){
                        xbcF[(size_t)mm*32 + (nn - 8)] = v;
                        if (nn < 24) BsL[mm - m0][nn - 8] = v;
                    }
                }
            }
        }
    }
    __syncthreads();
    // Phase 2: delta expansion + pack, fused chunk-local scan (h0 = 0).
    {
        int half = tid >> 8;
        int d = tid & 255;
        float4 dw0 = *(const float4*)&dtw[d*8];
        float4 dw1 = *(const float4*)&dtw[d*8 + 4];
        float bd = bias[d];
        float A0; bool structured;
        {
            float4 a0 = *(const float4*)&Alog[d*16];
            float4 a1 = *(const float4*)&Alog[d*16+4];
            float4 a2 = *(const float4*)&Alog[d*16+8];
            float4 a3 = *(const float4*)&Alog[d*16+12];
            float tmp[16] = {a0.x,a0.y,a0.z,a0.w,a1.x,a1.y,a1.z,a1.w,
                             a2.x,a2.y,a2.z,a2.w,a3.x,a3.y,a3.z,a3.w};
            float At[16];
#pragma unroll
            for (int s=0;s<16;s++) At[s] = -__expf(tmp[s]);
            structured = a_structured(At);
            A0 = At[0];
        }
        int b  = m0 >> 10;            // TSEQ = 1024
        int c  = ((m0 & 1023) >> 5) + half;
        f32x2 h2[8];
#pragma unroll
        for (int s=0;s<8;s++) h2[s] = (f32x2){0.f,0.f};
        float* h = (float*)h2;
        float sdv = 0.f;
#pragma unroll
        for (int t0 = 0; t0 < CSZ; t0 += 8){
            ushort_t uu[8];
#pragma unroll
            for (int k=0;k<8;k++)
                uu[k] = A[(size_t)(m0 + half*CSZ + t0 + k)*KT + d];
#pragma unroll
            for (int k=0;k<8;k++){
                int t = half*CSZ + t0 + k;
                const float* dt8 = dtS[t];
                float4 a0 = *(const float4*)&dt8[0];
                float4 a1 = *(const float4*)&dt8[4];
                float v = bd + a0.x*dw0.x + a0.y*dw0.y + a0.z*dw0.z + a0.w*dw0.w
                             + a1.x*dw1.x + a1.y*dw1.y + a1.z*dw1.z + a1.w*dw1.w;
                float delta = softplus_f(v);
                ushort_t dh = f2bf(delta);
                duB[(size_t)(m0 + t)*KT + d] =
                    ((unsigned int)dh << 16) | (unsigned int)uu[k];
                // inline pass1 (rounded values = what the scan consumes)
                float dlt = bf2f(dh);
                float uv  = bf2f(uu[k]);
                sdv += dlt;
                float duv = dlt*uv;
                const f32x2* Bp2 = (const f32x2*)&BsL[t][0];
                if (structured){
                    float p  = __expf(dlt*A0);
                    float p2 = p*p, p4 = p2*p2;
                    f32x2 fA = (f32x2){p, p2};
                    f32x2 fB = (f32x2){p2*p, p4};
                    f32x2 p4v = (f32x2){p4, p4};
                    f32x2 du2 = (f32x2){duv, duv};
#pragma unroll
                    for (int q=0;q<4;q++){
                        h2[2*q]   = fA*h2[2*q]   + du2*Bp2[2*q];
                        h2[2*q+1] = fB*h2[2*q+1] + du2*Bp2[2*q+1];
                        if (q < 3){ fA *= p4v; fB *= p4v; }
                    }
                } else {
#pragma unroll
                    for (int q=0;q<4;q++){
                        float4 aq = *(const float4*)&Alog[d*16 + 4*q];
                        const float* bq = &BsL[t][4*q];
                        h[4*q+0] = __expf(-dlt*__expf(aq.x))*h[4*q+0] + duv*bq[0];
                        h[4*q+1] = __expf(-dlt*__expf(aq.y))*h[4*q+1] + duv*bq[1];
                        h[4*q+2] = __expf(-dlt*__expf(aq.z))*h[4*q+2] + duv*bq[2];
                        h[4*q+3] = __expf(-dlt*__expf(aq.w))*h[4*q+3] + duv*bq[3];
                    }
                }
            }
        }
#pragma unroll
        for (int s=0;s<16;s++)
            hloc[((size_t)((b*NCH + c)*16 + s))*DI + d] = f2bf(h[s]);
        sd[(b*NCH + c)*DI + d] = sdv;
    }
}

// ---------------------------------------------------------------------------
// Prefix-combine over chunks (thread = (b,s,d)) — coalesced layout, bf16
// states (R18/R20 form).
__global__ __launch_bounds__(256) void scan_combine(
    const ushort_t* __restrict__ hloc, const float* __restrict__ sd,
    const float* __restrict__ Alog, ushort_t* __restrict__ hstart)
{
    int b = blockIdx.x, s = blockIdx.y;
    int d = threadIdx.x;
    float A = -__expf(Alog[d*16+s]);
    float hs = 0.f;
    for (int c = 0; c < NCH; c++){
        size_t base = ((size_t)((b*NCH + c)*16 + s))*DI + d;
        hstart[base] = f2bf(hs);
        float sdp = sd[(b*NCH + c)*DI + d];
        hs = __expf(sdp*A)*hs + bf2f(hloc[base]);
    }
}

// ---------------------------------------------------------------------------
// Fused scan pass 2 + out_proj + FFN (fast gelu) for a 32-token chunk.
// Phase A: packed-fp32 h/y recurrence (R22), TWO loads per token, depth-8
// double-buffer. h-init from bf16 hstart. Phase B: single-plane bf16 (R12).
__global__ __launch_bounds__(256,4) void scan_fused(
    const unsigned int* __restrict__ duB, const float* __restrict__ xbcF,
    const ushort_t* __restrict__ zB,
    const float* __restrict__ Alog, const float* __restrict__ Dp,
    const ushort_t* __restrict__ hstart,
    const ushort_t* __restrict__ oWh,
    const ushort_t* __restrict__ w1h,
    const float* __restrict__ b1,
    const ushort_t* __restrict__ w2h,
    const float* __restrict__ b2,
    ushort_t* __restrict__ hB)
{
    constexpr int YS = DI + 8;    // 264 shorts
    constexpr int OS = DM + 8;    // 136 shorts
    __shared__ __align__(16) ushort_t smem[CSZ*YS + CSZ*OS];   // 25600 B
    ushort_t* yB = smem;                      // [t*YS + d]
    ushort_t* oB = smem + CSZ*YS;             // [t*OS + n]
    float*    Bs = (float*)(smem + CSZ*YS);   // union with oB
    float*    Cs = Bs + CSZ*16;

    int b = blockIdx.x, c = blockIdx.y;
    int tid = threadIdx.x;
    int mbase = b*TSEQ + c*CSZ;
    for (int i = tid; i < CSZ*32; i += 256) {
        int t = i >> 5, s2 = i & 31;
        float v = xbcF[(size_t)(mbase+t)*32 + s2];
        if (s2 < 16) Bs[t*16+s2] = v; else Cs[t*16+s2-16] = v;
    }
    // ---- Phase A: scan
    {
        int d = tid;
        // group-0 register prefetch: overlaps barrier + A/hstart setup
        unsigned int du[2][8]; ushort_t zz[2][8];
#pragma unroll
        for (int k=0;k<8;k++){
            size_t m = (size_t)(mbase+k);
            du[0][k] = duB[m*DI + d];
            zz[0][k] = zB[m*DI + d];
        }
        float A0; bool structured;
        {
            float4 a0 = *(const float4*)&Alog[d*16];
            float4 a1 = *(const float4*)&Alog[d*16+4];
            float4 a2 = *(const float4*)&Alog[d*16+8];
            float4 a3 = *(const float4*)&Alog[d*16+12];
            float tmp[16] = {a0.x,a0.y,a0.z,a0.w,a1.x,a1.y,a1.z,a1.w,
                             a2.x,a2.y,a2.z,a2.w,a3.x,a3.y,a3.z,a3.w};
            float At[16];
#pragma unroll
            for (int s=0;s<16;s++) At[s] = -__expf(tmp[s]);
            structured = a_structured(At);
            A0 = At[0];
        }
        f32x2 h2[8];
        float* h = (float*)h2;
#pragma unroll
        for (int s=0;s<16;s++)
            h[s] = bf2f(hstart[((size_t)((b*NCH + c)*16 + s))*DI + d]);
        float Dd = Dp[d];
        __syncthreads();
        if (structured){
#pragma unroll
            for (int t0i = 0; t0i < CSZ/8; t0i++){
                int cur = t0i & 1, nxt = cur ^ 1;   // static after unroll
                if (t0i < CSZ/8 - 1){
#pragma unroll
                    for (int k=0;k<8;k++){
                        size_t m = (size_t)(mbase + (t0i+1)*8 + k);
                        du[nxt][k] = duB[m*DI + d];
                        zz[nxt][k] = zB[m*DI + d];
                    }
                }
#pragma unroll
                for (int k=0;k<8;k++){
                    int t = t0i*8 + k;
                    unsigned int pk_ = du[cur][k];
                    float dlt = bf2f((ushort_t)(pk_ >> 16));
                    float uv  = bf2f((ushort_t)(pk_ & 0xffffu));
                    float duv = dlt*uv;
                    float p  = __expf(dlt*A0);
                    float p2 = p*p, p4 = p2*p2;
                    f32x2 fA = (f32x2){p, p2};
                    f32x2 fB = (f32x2){p2*p, p4};
                    f32x2 p4v = (f32x2){p4, p4};
                    f32x2 du2 = (f32x2){duv, duv};
                    const f32x2* Bp2 = (const f32x2*)&Bs[t*16];
                    const f32x2* Cp2 = (const f32x2*)&Cs[t*16];
                    f32x2 yA = (f32x2){0.f,0.f};
                    f32x2 yBv = (f32x2){0.f,0.f};
#pragma unroll
                    for (int q=0;q<4;q++){
                        h2[2*q]   = fA*h2[2*q]   + du2*Bp2[2*q];
                        h2[2*q+1] = fB*h2[2*q+1] + du2*Bp2[2*q+1];
                        yA  += h2[2*q]*Cp2[2*q];
                        yBv += h2[2*q+1]*Cp2[2*q+1];
                        if (q < 3){ fA *= p4v; fB *= p4v; }
                    }
                    float y = (yA.x + yA.y) + (yBv.x + yBv.y);
                    yB[t*YS+d] = f2bf((y + uv*Dd) * silu_f(bf2f(zz[cur][k])));
                }
            }
        } else {
            // cold fallback: general A (reloaded from global per 4-state group)
            for (int t = 0; t < CSZ; t++){
                size_t m = (size_t)(mbase+t);
                unsigned int pk_ = duB[m*DI + d];
                float dlt = bf2f((ushort_t)(pk_ >> 16));
                float uv  = bf2f((ushort_t)(pk_ & 0xffffu));
                float zv  = bf2f(zB[m*DI + d]);
                float duv = dlt*uv;
                float y0=0.f, y1=0.f, y2=0.f, y3=0.f;
#pragma unroll
                for (int q=0;q<4;q++){
                    float4 aq = *(const float4*)&Alog[d*16 + 4*q];
                    const float* bq = &Bs[t*16 + 4*q];
                    const float* cq = &Cs[t*16 + 4*q];
                    h[4*q+0] = __expf(-dlt*__expf(aq.x))*h[4*q+0] + duv*bq[0]; y0 += h[4*q+0]*cq[0];
                    h[4*q+1] = __expf(-dlt*__expf(aq.y))*h[4*q+1] + duv*bq[1]; y1 += h[4*q+1]*cq[1];
                    h[4*q+2] = __expf(-dlt*__expf(aq.z))*h[4*q+2] + duv*bq[2]; y2 += h[4*q+2]*cq[2];
                    h[4*q+3] = __expf(-dlt*__expf(aq.w))*h[4*q+3] + duv*bq[3]; y3 += h[4*q+3]*cq[3];
                }
                float y = (y0+y1)+(y2+y3);
                yB[t*YS+d] = f2bf((y + uv*Dd) * silu_f(zv));
            }
        }
    }
    __syncthreads();   // yB done; Bs/Cs dead -> region2 reusable as oB
    // ---- Phase B (single-plane bf16 weights)
    int wave = tid>>6, lane = tid&63;
    int r = lane&15, g = lane>>4;
    // Stage 1: o[32][128] = y @ oW^T  (K=256)
    {
        f32x4 s1[2][2];
#pragma unroll
        for (int i=0;i<2;i++)
#pragma unroll
            for (int j=0;j<2;j++) s1[i][j] = (f32x4){0.f,0.f,0.f,0.f};
#pragma unroll
        for (int ks=0;ks<8;ks++){
            short8 ya[2];
#pragma unroll
            for (int i=0;i<2;i++)
                ya[i] = *(const short8*)&yB[(i*16+r)*YS + ks*32 + g*8];
            short8 wh_[2];
#pragma unroll
            for (int j=0;j<2;j++){
                size_t wa = (size_t)(wave*32 + j*16 + r)*256 + ks*32 + g*8;
                wh_[j] = *(const short8*)&oWh[wa];
            }
#pragma unroll
            for (int i=0;i<2;i++)
#pragma unroll
            for (int j=0;j<2;j++){
                s1[i][j] = MFMA16(ya[i], wh_[j], s1[i][j]);
            }
        }
#pragma unroll
        for (int i=0;i<2;i++)
#pragma unroll
        for (int j=0;j<2;j++)
#pragma unroll
        for (int q=0;q<4;q++){
            int t = i*16 + g*4 + q;
            int n = wave*32 + j*16 + r;
            oB[t*OS+n] = f2bf(s1[i][j][q]);
        }
    }
    __syncthreads();   // oB ready; yB reads done
    // Stage 2: f[32][256] = gelu(o @ w1^T + b1)  (K=128), into yB
    {
        f32x4 s2[2][4];
#pragma unroll
        for (int i=0;i<2;i++)
#pragma unroll
            for (int j=0;j<4;j++) s2[i][j] = (f32x4){0.f,0.f,0.f,0.f};
#pragma unroll
        for (int ks=0;ks<4;ks++){
            short8 oa[2];
#pragma unroll
            for (int i=0;i<2;i++)
                oa[i] = *(const short8*)&oB[(i*16+r)*OS + ks*32 + g*8];
            short8 wh_[4];
#pragma unroll
            for (int j=0;j<4;j++){
                size_t wa = (size_t)(wave*64 + j*16 + r)*128 + ks*32 + g*8;
                wh_[j] = *(const short8*)&w1h[wa];
            }
#pragma unroll
            for (int i=0;i<2;i++)
#pragma unroll
            for (int j=0;j<4;j++){
                s2[i][j] = MFMA16(oa[i], wh_[j], s2[i][j]);
            }
        }
#pragma unroll
        for (int i=0;i<2;i++)
#pragma unroll
        for (int j=0;j<4;j++)
#pragma unroll
        for (int q=0;q<4;q++){
            int t = i*16 + g*4 + q;
            int n = wave*64 + j*16 + r;
            yB[t*YS+n] = f2bf(gelu_f(s2[i][j][q] + b1[n]));
        }
    }
    __syncthreads();   // f (in yB) done
    // Stage 3: hnew[32][128] = f @ w2^T + b2  (K=256) -> global plane
    {
        f32x4 s3[2][2];
#pragma unroll
        for (int i=0;i<2;i++)
#pragma unroll
            for (int j=0;j<2;j++) s3[i][j] = (f32x4){0.f,0.f,0.f,0.f};
#pragma unroll
        for (int ks=0;ks<8;ks++){
            short8 fa[2];
#pragma unroll
            for (int i=0;i<2;i++)
                fa[i] = *(const short8*)&yB[(i*16+r)*YS + ks*32 + g*8];
            short8 wh_[2];
#pragma unroll
            for (int j=0;j<2;j++){
                size_t wa = (size_t)(wave*32 + j*16 + r)*256 + ks*32 + g*8;
                wh_[j] = *(const short8*)&w2h[wa];
            }
#pragma unroll
            for (int i=0;i<2;i++)
#pragma unroll
            for (int j=0;j<2;j++){
                s3[i][j] = MFMA16(fa[i], wh_[j], s3[i][j]);
            }
        }
#pragma unroll
        for (int i=0;i<2;i++)
#pragma unroll
        for (int j=0;j<2;j++)
#pragma unroll
        for (int q=0;q<4;q++){
            int t = i*16 + g*4 + q;
            int n = wave*32 + j*16 + r;
            hB[(size_t)(mbase + t)*DM + n] = f2bf(s3[i][j][q] + b2[n]);
        }
    }
}

// ---------------------------------------------------------------------------
// Final transpose: out[bv, d, n] = h[bv*1024+n, d]
__global__ __launch_bounds__(256) void final_transpose(
    const ushort_t* __restrict__ hB, float* __restrict__ out)
{
    int n0 = blockIdx.x*32, d0 = blockIdx.y*32, bv = blockIdx.z;
    __shared__ float ts[32][33];
    int tid = threadIdx.x;
    int c = tid & 31, r0 = tid >> 5;
    for (int rr = r0; rr < 32; rr += 8)
        ts[rr][c] = bf2f(hB[(size_t)(bv*TSEQ + n0 + rr)*DM + d0 + c]);
    __syncthreads();
    for (int rr = r0; rr < 32; rr += 8)
        out[(size_t)(bv*DM + d0 + rr)*TSEQ + n0 + c] = ts[c][rr];
}

// ---------------------------------------------------------------------------
extern "C" void kernel_launch(void* const* d_in, const int* in_sizes, int n_in,
                              void* d_out, int out_size, void* d_ws, size_t ws_size,
                              hipStream_t stream)
{
    const float* x     = (const float*)d_in[0];
    const float* Wp    = (const float*)d_in[1];
    const float* Wpb   = (const float*)d_in[2];
    const float* inW   = (const float*)d_in[3];
    const float* convW = (const float*)d_in[4];
    const float* convB = (const float*)d_in[5];
    const float* xpW   = (const float*)d_in[6];
    const float* dtW   = (const float*)d_in[7];
    const float* dtB   = (const float*)d_in[8];
    const float* Alog  = (const float*)d_in[9];
    const float* Dp    = (const float*)d_in[10];
    const float* outW  = (const float*)d_in[11];
    const float* l1W   = (const float*)d_in[12];
    const float* l1B   = (const float*)d_in[13];
    const float* l2W   = (const float*)d_in[14];
    const float* l2B   = (const float*)d_in[15];
    float* out = (float*)d_out;

    char* base = (char*)d_ws;
    size_t off = 0;
    auto alloc = [&](size_t bytes) { char* p = base + off; off += (bytes + 255) & ~(size_t)255; return p; };

    const size_t P128 = (size_t)MTOK*DM*2;     // [M][128] bf16 plane
    const size_t P256 = (size_t)MTOK*DI*2;     // [M][256] bf16 plane

    ushort_t* hB  = (ushort_t*)alloc(P128);
    unsigned int* duB = (unsigned int*)alloc((size_t)MTOK*DI*4);  // delta|u packed
    float* xbcF   = (float*)alloc((size_t)MTOK*32*4);             // B|C fp32
    ushort_t* zB  = (ushort_t*)alloc(P256);
    ushort_t* xcB = (ushort_t*)alloc(P256);
    ushort_t* hloc   = (ushort_t*)alloc((size_t)BSEQ*NCH*DS*DI*2);  // bf16 states
    ushort_t* hstart = (ushort_t*)alloc((size_t)BSEQ*NCH*DS*DI*2);  // bf16 states
    float* sd     = (float*)alloc((size_t)BSEQ*NCH*DI*4);
    ushort_t* inWh  = (ushort_t*)alloc((size_t)512*128*2);
    ushort_t* wcS   = (ushort_t*)alloc((size_t)48*256*2);
    ushort_t* outWh = (ushort_t*)alloc((size_t)128*256*2);
    ushort_t* l1Wh  = (ushort_t*)alloc((size_t)256*128*2);
    ushort_t* l2Wh  = (ushort_t*)alloc((size_t)128*256*2);

    patch_embed<<<dim3(32,16), 256, 0, stream>>>(x, Wp, Wpb, hB);

    for (int L = 0; L < L_LAYERS; L++) {
        const float* inW_l   = inW   + (size_t)L*2*DI*DM;
        const float* convW_l = convW + (size_t)L*DI*4;
        const float* convB_l = convB + (size_t)L*DI;
        const float* xpW_l   = xpW   + (size_t)L*(DTR+2*DS)*DI;
        const float* dtW_l   = dtW   + (size_t)L*DI*DTR;
        const float* dtB_l   = dtB   + (size_t)L*DI;
        const float* Alog_l  = Alog  + (size_t)L*DI*DS;
        const float* Dp_l    = Dp    + (size_t)L*DI;
        const float* outW_l  = outW  + (size_t)L*DM*DI;
        const float* l1W_l   = l1W   + (size_t)L*DFF*DM;
        const float* l1B_l   = l1B   + (size_t)L*DFF;
        const float* l2W_l   = l2W   + (size_t)L*DM*DFF;
        const float* l2B_l   = l2B   + (size_t)L*DM;

        prep_layer<<<(PREP_ELEMS+255)/256, 256, 0, stream>>>(
            inW_l, xpW_l, outW_l, l1W_l, l2W_l,
            inWh, wcS, outWh, l1Wh, l2Wh);

        gemm_inproj_conv<<<dim3(MTOK/256, 8), 256, 0, stream>>>(
            hB, inWh, convW_l, convB_l, xcB, zB);
        gemm_xproj<<<dim3(MTOK/64), 512, 0, stream>>>(
            xcB, wcS, dtW_l, dtB_l, Alog_l, duB, xbcF, hloc, sd);
        scan_combine<<<dim3(BSEQ, DS), 256, 0, stream>>>(
            hloc, sd, Alog_l, hstart);
        scan_fused<<<dim3(BSEQ, NCH), 256, 0, stream>>>(
            duB, xbcF, zB, Alog_l, Dp_l, hstart,
            outWh, l1Wh, l1B_l, l2Wh, l2B_l, hB);
    }

    final_transpose<<<dim3(TSEQ/32, DM/32, BSEQ), 256, 0, stream>>>(hB, out);
}